// Round 1
// baseline (442.744 us; speedup 1.0000x reference)
//
#include <hip/hip_runtime.h>
#include <hip/hip_fp16.h>
#include <cfloat>
#include <cstdint>
#include <cstddef>

#define N_NODES 100000
#define N_EDGES 1600000
#define G_GRAPHS 64
#define BKT_SHIFT 9
#define BKT_NODES (1 << BKT_SHIFT)                              // 512
#define NBKT ((N_NODES + BKT_NODES - 1) >> BKT_SHIFT)           // 196

// ---------------------------------------------------------------------------
// Dual GEMM, single-pass: O0 = act(A)@W0 (fp16 if HALF0), O1 = act(A)@W1.
// ---------------------------------------------------------------------------
template <int K, int J, bool FUSE, bool HALF0>
__launch_bounds__(256) __global__
void gemm_dual(const float* __restrict__ A, const float* __restrict__ W0,
               const float* __restrict__ W1, const float* __restrict__ bias,
               void* __restrict__ O0v, float* __restrict__ O1, int n) {
  constexpr int BK = 64;
  constexpr int CPT = J / 32;
  __shared__ __align__(16) float As[32][BK];
  __shared__ __align__(16) float W0t[J][BK + 4];
  __shared__ __align__(16) float W1t[J][BK + 4];
  const int tid = threadIdx.x;
  const int n0 = blockIdx.x * 32;
  const int tr = tid >> 5;
  const int tc = tid & 31;

  float acc[4][CPT][2];
#pragma unroll
  for (int i = 0; i < 4; ++i)
#pragma unroll
    for (int j = 0; j < CPT; ++j) {
      acc[i][j][0] = 0.f;
      acc[i][j][1] = 0.f;
    }

  for (int kc = 0; kc < K; kc += BK) {
    for (int i = tid; i < 32 * BK / 4; i += 256) {
      const int node = i / (BK / 4);
      const int kg = i % (BK / 4);
      float4 v = make_float4(0.f, 0.f, 0.f, 0.f);
      if (n0 + node < n) {
        v = reinterpret_cast<const float4*>(
            A)[(size_t)(n0 + node) * (K / 4) + kc / 4 + kg];
        if constexpr (FUSE) {
          const float4 b =
              reinterpret_cast<const float4*>(bias)[kc / 4 + kg];
          v.x = fmaxf(v.x + b.x, 0.f);
          v.y = fmaxf(v.y + b.y, 0.f);
          v.z = fmaxf(v.z + b.z, 0.f);
          v.w = fmaxf(v.w + b.w, 0.f);
        }
      }
      reinterpret_cast<float4*>(&As[node][0])[kg] = v;
    }
    for (int i = tid; i < BK * J; i += 256) {
      const int k = i / J;
      const int j = i % J;
      W0t[j][k] = W0[(size_t)(kc + k) * J + j];
      W1t[j][k] = W1[(size_t)(kc + k) * J + j];
    }
    __syncthreads();

#pragma unroll 2
    for (int k4 = 0; k4 < BK / 4; ++k4) {
      float4 a[4];
#pragma unroll
      for (int i = 0; i < 4; ++i)
        a[i] = reinterpret_cast<const float4*>(&As[tr * 4 + i][0])[k4];
      float4 w0[CPT], w1[CPT];
#pragma unroll
      for (int j = 0; j < CPT; ++j) {
        w0[j] = *reinterpret_cast<const float4*>(&W0t[tc + 32 * j][k4 * 4]);
        w1[j] = *reinterpret_cast<const float4*>(&W1t[tc + 32 * j][k4 * 4]);
      }
#pragma unroll
      for (int i = 0; i < 4; ++i)
#pragma unroll
        for (int j = 0; j < CPT; ++j) {
          acc[i][j][0] = fmaf(a[i].x, w0[j].x, acc[i][j][0]);
          acc[i][j][0] = fmaf(a[i].y, w0[j].y, acc[i][j][0]);
          acc[i][j][0] = fmaf(a[i].z, w0[j].z, acc[i][j][0]);
          acc[i][j][0] = fmaf(a[i].w, w0[j].w, acc[i][j][0]);
          acc[i][j][1] = fmaf(a[i].x, w1[j].x, acc[i][j][1]);
          acc[i][j][1] = fmaf(a[i].y, w1[j].y, acc[i][j][1]);
          acc[i][j][1] = fmaf(a[i].z, w1[j].z, acc[i][j][1]);
          acc[i][j][1] = fmaf(a[i].w, w1[j].w, acc[i][j][1]);
        }
    }
    __syncthreads();
  }

#pragma unroll
  for (int i = 0; i < 4; ++i) {
    const int node = n0 + tr * 4 + i;
    if (node < n) {
      if constexpr (HALF0) {
        __half* O0 = (__half*)O0v;
#pragma unroll
        for (int j = 0; j < CPT; ++j)
          O0[(size_t)node * J + tc + 32 * j] = __float2half(acc[i][j][0]);
      } else {
        float* O0 = (float*)O0v;
#pragma unroll
        for (int j = 0; j < CPT; ++j)
          O0[(size_t)node * J + tc + 32 * j] = acc[i][j][0];
      }
#pragma unroll
      for (int j = 0; j < CPT; ++j)
        O1[(size_t)node * J + tc + 32 * j] = acc[i][j][1];
    }
  }
}

// ---------------------------------------------------------------------------
// CSR build: bucket hist (LDS only) -> bucket scan -> partition ->
// per-bucket deg/row/scatter (all per-node RMW in LDS).
// ---------------------------------------------------------------------------
__launch_bounds__(256) __global__
void histB_kernel(const int* __restrict__ ei, int* __restrict__ bhist) {
  __shared__ int lb[NBKT];
  for (int i = threadIdx.x; i < NBKT; i += 256) lb[i] = 0;
  __syncthreads();
  const int e0 = blockIdx.x * 1024 + threadIdx.x;
#pragma unroll
  for (int k = 0; k < 4; ++k) {
    const int e = e0 + k * 256;
    if (e < N_EDGES) atomicAdd(&lb[ei[N_EDGES + e] >> BKT_SHIFT], 1);
  }
  __syncthreads();
  for (int i = threadIdx.x; i < NBKT; i += 256)
    if (lb[i]) atomicAdd(&bhist[i], lb[i]);
}

__launch_bounds__(256) __global__
void bscan_kernel(const int* __restrict__ bhist, int* __restrict__ bbase,
                  int* __restrict__ bcursor) {
  __shared__ int ls[256];
  const int tid = threadIdx.x;
  const int v = (tid < NBKT) ? bhist[tid] : 0;
  ls[tid] = v;
  __syncthreads();
  for (int d = 1; d < 256; d <<= 1) {
    const int t = (tid >= d) ? ls[tid - d] : 0;
    __syncthreads();
    ls[tid] += t;
    __syncthreads();
  }
  if (tid < NBKT) {
    const int ex = ls[tid] - v;
    bbase[tid] = ex;
    bcursor[tid] = ex;
  }
}

// phase A: scatter edges into bucket-contiguous staging (dense writes).
__launch_bounds__(1024) __global__
void partA_kernel(const int* __restrict__ ei, int* __restrict__ bcursor,
                  int2* __restrict__ staging) {
  __shared__ int lh[NBKT];
  __shared__ int lbase[NBKT];
  const int tid = threadIdx.x;
  for (int i = tid; i < NBKT; i += 1024) lh[i] = 0;
  __syncthreads();
  const int e0 = blockIdx.x * 4096 + tid;
  int s[4], d[4];
#pragma unroll
  for (int k = 0; k < 4; ++k) {
    const int e = e0 + k * 1024;
    const bool ok = e < N_EDGES;
    s[k] = ok ? ei[e] : 0;
    d[k] = ok ? ei[N_EDGES + e] : -1;
    if (ok) atomicAdd(&lh[d[k] >> BKT_SHIFT], 1);
  }
  __syncthreads();
  for (int i = tid; i < NBKT; i += 1024) {
    const int c = lh[i];
    lbase[i] = c ? atomicAdd(&bcursor[i], c) : 0;
    lh[i] = 0;
  }
  __syncthreads();
#pragma unroll
  for (int k = 0; k < 4; ++k) {
    if (d[k] >= 0) {
      const int b = d[k] >> BKT_SHIFT;
      const int p = lbase[b] + atomicAdd(&lh[b], 1);
      staging[p] = make_int2(s[k], d[k]);
    }
  }
}

// phase B: per-bucket deg count (LDS), 512-scan -> row, then local scatter.
__launch_bounds__(256) __global__
void partB_kernel(const int2* __restrict__ staging,
                  const int* __restrict__ bbase, const int* __restrict__ bhist,
                  int* __restrict__ deg, int* __restrict__ row,
                  int* __restrict__ csr_src) {
  __shared__ int ldeg[BKT_NODES];
  __shared__ int lsc[256];
  const int b = blockIdx.x;
  const int tid = threadIdx.x;
  const int node0 = b << BKT_SHIFT;
  ldeg[2 * tid] = 0;
  ldeg[2 * tid + 1] = 0;
  __syncthreads();
  const int start = bbase[b];
  const int cnt = bhist[b];
  for (int i = tid; i < cnt; i += 256)
    atomicAdd(&ldeg[staging[start + i].y - node0], 1);
  __syncthreads();
  // 512-wide exclusive scan (2 elems/thread)
  const int d0 = ldeg[2 * tid];
  const int d1 = ldeg[2 * tid + 1];
  const int psum = d0 + d1;
  lsc[tid] = psum;
  __syncthreads();
  for (int d = 1; d < 256; d <<= 1) {
    const int t = (tid >= d) ? lsc[tid - d] : 0;
    __syncthreads();
    lsc[tid] += t;
    __syncthreads();
  }
  const int ex = lsc[tid] - psum + start;  // global CSR offset
  const int n0 = node0 + 2 * tid;
  if (n0 < N_NODES) {
    deg[n0] = d0;
    row[n0] = ex;
  }
  if (n0 + 1 < N_NODES) {
    deg[n0 + 1] = d1;
    row[n0 + 1] = ex + d0;
  }
  __syncthreads();
  // reuse ldeg as write cursor
  ldeg[2 * tid] = ex;
  ldeg[2 * tid + 1] = ex + d0;
  __syncthreads();
  for (int i = tid; i < cnt; i += 256) {
    const int2 e = staging[start + i];
    const int p = atomicAdd(&ldeg[e.y - node0], 1);
    csr_src[p] = e.x;
  }
}

// ---------------------------------------------------------------------------
// Layer 1 fused softmax-aggregate. H=2, C=32. One wave per node; the two
// 32-lane halves process 2 edges simultaneously, each lane holding a
// channel PAIR (fp16x2 gather). Head = 16-lane group; 4-level xor reduce.
//
// v2: coalesced CSR load (64 entries/wave, exec-masked) + ds_bpermute
// distribution replaces the per-quad broadcast-load chains; gathers for up
// to 16 edge-pairs are issued before any compute (tiered on wave-uniform
// deg) to maximize memory-level parallelism on the LLC-latency gathers.
// ---------------------------------------------------------------------------
__launch_bounds__(256) __global__
void gat1_kernel(const __half* __restrict__ xlh, const float* __restrict__ xr,
                 const float* __restrict__ att, const int* __restrict__ row,
                 const int* __restrict__ deg, const int* __restrict__ csr_src,
                 float* __restrict__ agg) {
  const int n =
      __builtin_amdgcn_readfirstlane(blockIdx.x * 4 + (threadIdx.x >> 6));
  if (n >= N_NODES) return;
  const int lane = threadIdx.x & 63;
  const int half = lane >> 5;  // edge slot (A/B)
  const int l = lane & 31;     // channel-pair index: channels 2l, 2l+1
  const int r0 = __builtin_amdgcn_readfirstlane(row[n]);
  const int dg = __builtin_amdgcn_readfirstlane(deg[n]);

  const float2 xrv =
      *reinterpret_cast<const float2*>(xr + ((size_t)n << 6) + 2 * l);
  const float2 attv = *reinterpret_cast<const float2*>(att + 2 * l);

  float s = 0.f;
  float2 acc = make_float2(0.f, 0.f);

  // issue gathers for pairs q0..q0+3 (edges 2q+half) of the current chunk
  auto issue = [&](int q0, __half2 (&dst)[4], int srcv) {
#pragma unroll
    for (int k = 0; k < 4; ++k) {
      const int sel = __shfl(srcv, 2 * (q0 + k) + half);
      dst[k] = *reinterpret_cast<const __half2*>(
          (const char*)xlh + (((size_t)(unsigned)sel) << 7) + 4 * l);
    }
  };
  auto compute = [&](int q0, __half2 (&buf)[4], int rem) {
#pragma unroll
    for (int k = 0; k < 4; ++k) {
      const float2 a = __half22float2(buf[k]);
      float vx = a.x + xrv.x, vy = a.y + xrv.y;
      vx = fmaxf(vx, 0.2f * vx);
      vy = fmaxf(vy, 0.2f * vy);
      float p = fmaf(vy, attv.y, vx * attv.x);
      p += __shfl_xor(p, 1);
      p += __shfl_xor(p, 2);
      p += __shfl_xor(p, 4);
      p += __shfl_xor(p, 8);  // 16-lane head-group sum (butterfly: all lanes)
      float e = __expf(p);
      e = (2 * (q0 + k) + half < rem) ? e : 0.f;
      s += e;
      acc.x = fmaf(e, a.x, acc.x);
      acc.y = fmaf(e, a.y, acc.y);
    }
  };

  for (int c0 = 0; c0 < dg; c0 += 64) {
    const int rem = dg - c0;  // wave-uniform; may exceed 64 (capped by chunk)
    int srcv = 0;
    if (lane < rem) srcv = csr_src[r0 + c0 + lane];  // coalesced, exec-masked
    const int P = min(32, (rem + 1) >> 1);  // edge pairs in this chunk
    __half2 b0[4], b1[4], b2[4], b3[4];
    issue(0, b0, srcv);
    if (P > 4) issue(4, b1, srcv);
    if (P > 8) {
      issue(8, b2, srcv);
      if (P > 12) issue(12, b3, srcv);
    }
    compute(0, b0, rem);
    if (P > 4) {
      compute(4, b1, rem);
      if (P > 8) {
        compute(8, b2, rem);
        if (P > 12) {
          compute(12, b3, rem);
          for (int t = 16; t < P; t += 4) {  // rare tail (deg > 32)
            issue(t, b0, srcv);
            compute(t, b0, rem);
          }
        }
      }
    }
  }

  // merge the two edge slots
  s += __shfl_xor(s, 32);
  acc.x += __shfl_xor(acc.x, 32);
  acc.y += __shfl_xor(acc.y, 32);
  const float inv = s > 0.f ? 1.f / s : 0.f;
  if (half == 0)
    *reinterpret_cast<float2*>(agg + ((size_t)n << 6) + 2 * l) =
        make_float2(acc.x * inv, acc.y * inv);
}

// ---------------------------------------------------------------------------
// Layer 2 fused: H=1, C=32. Four 16-lane groups process 4 edges at once,
// each lane holds a channel pair. Butterfly merges leave all lanes with the
// full result. Epilogue: bias+relu -> h2, gate scalar inline.
// v2: same coalesced-CSR + up-front-gather restructure as gat1; gate matvec
// split across the two 32-lane halves (16 iters each).
// ---------------------------------------------------------------------------
__launch_bounds__(256) __global__
void gat2_kernel(const __half* __restrict__ xlh, const float* __restrict__ xr,
                 const float* __restrict__ att, const int* __restrict__ row,
                 const int* __restrict__ deg, const int* __restrict__ csr_src,
                 const float* __restrict__ b2, const float* __restrict__ g1w,
                 const float* __restrict__ g1b, const float* __restrict__ g2w,
                 const float* __restrict__ g2b, float* __restrict__ h2,
                 float* __restrict__ gate) {
  const int n =
      __builtin_amdgcn_readfirstlane(blockIdx.x * 4 + (threadIdx.x >> 6));
  if (n >= N_NODES) return;
  const int lane = threadIdx.x & 63;
  const int g = lane >> 4;   // edge group 0..3
  const int m = lane & 15;   // channel-pair index: channels 2m, 2m+1

  const int r0 = __builtin_amdgcn_readfirstlane(row[n]);
  const int dg = __builtin_amdgcn_readfirstlane(deg[n]);

  const float2 xrv =
      *reinterpret_cast<const float2*>(xr + (size_t)n * 32 + 2 * m);
  const float2 attv = *reinterpret_cast<const float2*>(att + 2 * m);

  float s = 0.f;
  float2 acc = make_float2(0.f, 0.f);

  // issue gathers for quads q0..q0+3 (edges 4q+g) of the current chunk
  auto issue = [&](int q0, __half2 (&dst)[4], int srcv) {
#pragma unroll
    for (int k = 0; k < 4; ++k) {
      const int sel = __shfl(srcv, 4 * (q0 + k) + g);
      dst[k] = *reinterpret_cast<const __half2*>(
          (const char*)xlh + (((size_t)(unsigned)sel) << 6) + 4 * m);
    }
  };
  auto compute = [&](int q0, __half2 (&buf)[4], int rem) {
#pragma unroll
    for (int k = 0; k < 4; ++k) {
      const float2 a = __half22float2(buf[k]);
      float vx = a.x + xrv.x, vy = a.y + xrv.y;
      vx = fmaxf(vx, 0.2f * vx);
      vy = fmaxf(vy, 0.2f * vy);
      float p = fmaf(vy, attv.y, vx * attv.x);
      p += __shfl_xor(p, 1);
      p += __shfl_xor(p, 2);
      p += __shfl_xor(p, 4);
      p += __shfl_xor(p, 8);  // 16-lane (edge) sum
      float e = __expf(p);
      e = (4 * (q0 + k) + g < rem) ? e : 0.f;
      s += e;
      acc.x = fmaf(e, a.x, acc.x);
      acc.y = fmaf(e, a.y, acc.y);
    }
  };

  for (int c0 = 0; c0 < dg; c0 += 64) {
    const int rem = dg - c0;
    int srcv = 0;
    if (lane < rem) srcv = csr_src[r0 + c0 + lane];  // coalesced, exec-masked
    const int Q = min(16, (rem + 3) >> 2);  // edge quads in this chunk
    __half2 b0[4], b1[4], b2v_[4], b3[4];
    issue(0, b0, srcv);
    if (Q > 4) {
      issue(4, b1, srcv);
      if (Q > 8) {
        issue(8, b2v_, srcv);
        if (Q > 12) issue(12, b3, srcv);
      }
    }
    compute(0, b0, rem);
    if (Q > 4) {
      compute(4, b1, rem);
      if (Q > 8) {
        compute(8, b2v_, rem);
        if (Q > 12) compute(12, b3, rem);
      }
    }
  }

  // merge the 4 edge groups (butterfly: all lanes get totals)
  s += __shfl_xor(s, 16);
  s += __shfl_xor(s, 32);
  acc.x += __shfl_xor(acc.x, 16);
  acc.x += __shfl_xor(acc.x, 32);
  acc.y += __shfl_xor(acc.y, 16);
  acc.y += __shfl_xor(acc.y, 32);
  const float inv = s > 0.f ? 1.f / s : 0.f;
  const float2 b2v = *reinterpret_cast<const float2*>(b2 + 2 * m);
  const float2 hv2 = make_float2(fmaxf(acc.x * inv + b2v.x, 0.f),
                                 fmaxf(acc.y * inv + b2v.y, 0.f));
  if (g == 0)
    *reinterpret_cast<float2*>(h2 + (size_t)n * 32 + 2 * m) = hv2;

  // redistribute to 1-channel-per-lane layout for the gate matvec
  const int c = lane & 31;
  const float hx = __shfl(hv2.x, c >> 1, 32);
  const float hy = __shfl(hv2.y, c >> 1, 32);
  const float hv = (c & 1) ? hy : hx;
  // split the 32-k dot across the two 32-lane halves: 16 iters each
  const int k0 = (lane >> 5) << 4;  // 0 or 16
  float sg = 0.f;
#pragma unroll
  for (int k = 0; k < 16; ++k) {
    const int kk = k0 + k;
    sg = fmaf(__shfl(hv, kk, 32), g1w[kk * 32 + c], sg);
  }
  sg += __shfl_xor(sg, 32);          // merge halves
  sg = fmaxf(sg + g1b[c], 0.f);
  float pg = sg * g2w[c];
  pg += __shfl_xor(pg, 1);
  pg += __shfl_xor(pg, 2);
  pg += __shfl_xor(pg, 4);
  pg += __shfl_xor(pg, 8);
  pg += __shfl_xor(pg, 16);
  if (lane == 0) gate[n] = pg + g2b[0];
}

// ---------------------------------------------------------------------------
__launch_bounds__(256) __global__
void gepool_kernel(const float* __restrict__ h2, const int* __restrict__ batch,
                   const float* __restrict__ gate, float* __restrict__ gd,
                   float* __restrict__ pooled) {
  __shared__ float pool[G_GRAPHS * 32];
  __shared__ float gdb[G_GRAPHS];
  const int tid = threadIdx.x;
  for (int i = tid; i < G_GRAPHS * 32; i += 256) pool[i] = 0.f;
  if (tid < G_GRAPHS) gdb[tid] = 0.f;
  __syncthreads();
  const int c = tid & 31;
  const int hw = tid >> 5;
  const int start = blockIdx.x * 256;
  const int end = min(N_NODES, start + 256);
  for (int n = start + hw; n < end; n += 8) {
    const int b = batch[n];
    const float ge = __expf(gate[n]);
    atomicAdd(&pool[b * 32 + c], ge * h2[(size_t)n * 32 + c]);
    if (c == 0) atomicAdd(&gdb[b], ge);
  }
  __syncthreads();
  for (int i = tid; i < G_GRAPHS * 32; i += 256)
    if (pool[i] != 0.f) unsafeAtomicAdd(&pooled[i], pool[i]);
  if (tid < G_GRAPHS && gdb[tid] != 0.f) unsafeAtomicAdd(&gd[tid], gdb[tid]);
}

__launch_bounds__(64) __global__
void final_kernel(const float* __restrict__ pooled, const float* __restrict__ gd,
                  const float* __restrict__ l1w, const float* __restrict__ l1b,
                  const float* __restrict__ l2w, const float* __restrict__ l2b,
                  float* __restrict__ out) {
  const int g = blockIdx.x;
  const int lane = threadIdx.x;
  if (lane >= 32) return;
  const float invgd = 1.f / gd[g];
  float s = l1b[lane];
#pragma unroll
  for (int k = 0; k < 32; ++k)
    s = fmaf(pooled[g * 32 + k] * invgd, l1w[k * 32 + lane], s);
  s = fmaxf(s, 0.f);
  float p = s * l2w[lane];
  p += __shfl_xor(p, 1);
  p += __shfl_xor(p, 2);
  p += __shfl_xor(p, 4);
  p += __shfl_xor(p, 8);
  p += __shfl_xor(p, 16);
  if (lane == 0) out[g] = p + l2b[0];
}

// ---------------------------------------------------------------------------
extern "C" void kernel_launch(void* const* d_in, const int* in_sizes, int n_in,
                              void* d_out, int out_size, void* d_ws,
                              size_t ws_size, hipStream_t stream) {
  const float* x    = (const float*)d_in[0];
  const int*   ei   = (const int*)d_in[1];
  const int*   batch= (const int*)d_in[2];
  const float* Wl1  = (const float*)d_in[3];
  const float* Wr1  = (const float*)d_in[4];
  const float* att1 = (const float*)d_in[5];
  const float* b1   = (const float*)d_in[6];
  const float* Wl2  = (const float*)d_in[7];
  const float* Wr2  = (const float*)d_in[8];
  const float* att2 = (const float*)d_in[9];
  const float* b2   = (const float*)d_in[10];
  const float* g1w  = (const float*)d_in[11];
  const float* g1b  = (const float*)d_in[12];
  const float* g2w  = (const float*)d_in[13];
  const float* g2b  = (const float*)d_in[14];
  const float* l1w  = (const float*)d_in[15];
  const float* l1b  = (const float*)d_in[16];
  const float* l2w  = (const float*)d_in[17];
  const float* l2b  = (const float*)d_in[18];
  float* out = (float*)d_out;

  // ---- workspace layout ----
  int* bhist   = (int*)d_ws;            // NBKT (zeroed)
  int* bbase   = bhist + NBKT;          // NBKT
  int* bcursor = bbase + NBKT;          // NBKT
  int* deg     = bcursor + NBKT;        // N (written coalesced by partB)
  int* row     = deg + N_NODES;         // N
  int* csr_src = row + N_NODES;         // E + 16 pad
  int2* staging = (int2*)(csr_src + N_EDGES + 16);  // E int2
  float* fbase = (float*)(staging + N_EDGES);
  float* xr1  = fbase;                         // N*64
  float* agg1 = xr1 + (size_t)N_NODES * 64;    // N*64
  float* gate = agg1 + (size_t)N_NODES * 64;   // N
  float* gd   = gate + N_NODES;                // 64
  float* pooled = gd + G_GRAPHS;               // 64*32
  __half* xl1h = (__half*)(pooled + G_GRAPHS * 32);  // N*64 half
  // layer-2 aliases (stream-ordered producers/consumers)
  __half* xl2h = xl1h;                         // N*32 half
  float* xr2 = xr1;                            // N*32 (first half of xr1)
  float* h2  = xr1 + (size_t)N_NODES * 32;     // N*32 (second half of xr1)

  hipMemsetAsync(bhist, 0, (size_t)NBKT * sizeof(int), stream);
  hipMemsetAsync(gd, 0, (size_t)(G_GRAPHS + G_GRAPHS * 32) * sizeof(float), stream);

  // CSR build: bucket hist -> scan -> partition -> per-bucket deg/row/scatter
  histB_kernel<<<(N_EDGES + 1023) / 1024, 256, 0, stream>>>(ei, bhist);
  bscan_kernel<<<1, 256, 0, stream>>>(bhist, bbase, bcursor);
  partA_kernel<<<(N_EDGES + 4095) / 4096, 1024, 0, stream>>>(ei, bcursor,
                                                             staging);
  partB_kernel<<<NBKT, 256, 0, stream>>>(staging, bbase, bhist, deg, row,
                                         csr_src);

  // Layer 1 (xl staged fp16)
  gemm_dual<128, 64, false, true><<<(N_NODES + 31) / 32, 256, 0, stream>>>(
      x, Wl1, Wr1, nullptr, (void*)xl1h, xr1, N_NODES);
  gat1_kernel<<<(N_NODES + 3) / 4, 256, 0, stream>>>(xl1h, xr1, att1, row, deg,
                                                     csr_src, agg1);

  // Layer 2 (bias1+relu fused into A-load; gate fused into epilogue)
  gemm_dual<64, 32, true, true><<<(N_NODES + 31) / 32, 256, 0, stream>>>(
      agg1, Wl2, Wr2, b1, (void*)xl2h, xr2, N_NODES);
  gat2_kernel<<<(N_NODES + 3) / 4, 256, 0, stream>>>(
      xl2h, xr2, att2, row, deg, csr_src, b2, g1w, g1b, g2w, g2b, h2, gate);

  // Pooling + head (no-max graph softmax)
  gepool_kernel<<<(N_NODES + 255) / 256, 256, 0, stream>>>(h2, batch, gate, gd,
                                                           pooled);
  final_kernel<<<64, 64, 0, stream>>>(pooled, gd, l1w, l1b, l2w, l2b, out);
}

// Round 4
// 423.091 us; speedup vs baseline: 1.0465x; 1.0465x over previous
//
#include <hip/hip_runtime.h>
#include <hip/hip_fp16.h>
#include <cfloat>
#include <cstdint>
#include <cstddef>

#define N_NODES 100000
#define N_EDGES 1600000
#define G_GRAPHS 64
#define BKT_SHIFT 9
#define BKT_NODES (1 << BKT_SHIFT)                              // 512
#define NBKT ((N_NODES + BKT_NODES - 1) >> BKT_SHIFT)           // 196

typedef _Float16 hvec2 __attribute__((ext_vector_type(2)));

// v_dot2_f32_f16: p = a.x*b.x + a.y*b.y + c (f32 accumulate)
static __device__ __forceinline__ float fdot2(hvec2 a, hvec2 b, float c) {
#if __has_builtin(__builtin_amdgcn_fdot2)
  return __builtin_amdgcn_fdot2(a, b, c, false);
#else
  return fmaf((float)a.y, (float)b.y, fmaf((float)a.x, (float)b.x, c));
#endif
}

// packed leaky-relu: max(v, 0.2*v)  (v_pk_mul_f16 + v_pk_max_f16)
static __device__ __forceinline__ hvec2 leaky2(hvec2 v) {
  return __builtin_elementwise_max(v, v * (_Float16)0.2f);
}

// ---------------------------------------------------------------------------
// Dual GEMM, single-pass: O0 = act(A)@W0 (fp16 if HALF0), O1 = act(A)@W1.
// ---------------------------------------------------------------------------
template <int K, int J, bool FUSE, bool HALF0>
__launch_bounds__(256) __global__
void gemm_dual(const float* __restrict__ A, const float* __restrict__ W0,
               const float* __restrict__ W1, const float* __restrict__ bias,
               void* __restrict__ O0v, float* __restrict__ O1, int n) {
  constexpr int BK = 64;
  constexpr int CPT = J / 32;
  __shared__ __align__(16) float As[32][BK];
  __shared__ __align__(16) float W0t[J][BK + 4];
  __shared__ __align__(16) float W1t[J][BK + 4];
  const int tid = threadIdx.x;
  const int n0 = blockIdx.x * 32;
  const int tr = tid >> 5;
  const int tc = tid & 31;

  float acc[4][CPT][2];
#pragma unroll
  for (int i = 0; i < 4; ++i)
#pragma unroll
    for (int j = 0; j < CPT; ++j) {
      acc[i][j][0] = 0.f;
      acc[i][j][1] = 0.f;
    }

  for (int kc = 0; kc < K; kc += BK) {
    for (int i = tid; i < 32 * BK / 4; i += 256) {
      const int node = i / (BK / 4);
      const int kg = i % (BK / 4);
      float4 v = make_float4(0.f, 0.f, 0.f, 0.f);
      if (n0 + node < n) {
        v = reinterpret_cast<const float4*>(
            A)[(size_t)(n0 + node) * (K / 4) + kc / 4 + kg];
        if constexpr (FUSE) {
          const float4 b =
              reinterpret_cast<const float4*>(bias)[kc / 4 + kg];
          v.x = fmaxf(v.x + b.x, 0.f);
          v.y = fmaxf(v.y + b.y, 0.f);
          v.z = fmaxf(v.z + b.z, 0.f);
          v.w = fmaxf(v.w + b.w, 0.f);
        }
      }
      reinterpret_cast<float4*>(&As[node][0])[kg] = v;
    }
    for (int i = tid; i < BK * J; i += 256) {
      const int k = i / J;
      const int j = i % J;
      W0t[j][k] = W0[(size_t)(kc + k) * J + j];
      W1t[j][k] = W1[(size_t)(kc + k) * J + j];
    }
    __syncthreads();

#pragma unroll 2
    for (int k4 = 0; k4 < BK / 4; ++k4) {
      float4 a[4];
#pragma unroll
      for (int i = 0; i < 4; ++i)
        a[i] = reinterpret_cast<const float4*>(&As[tr * 4 + i][0])[k4];
      float4 w0[CPT], w1[CPT];
#pragma unroll
      for (int j = 0; j < CPT; ++j) {
        w0[j] = *reinterpret_cast<const float4*>(&W0t[tc + 32 * j][k4 * 4]);
        w1[j] = *reinterpret_cast<const float4*>(&W1t[tc + 32 * j][k4 * 4]);
      }
#pragma unroll
      for (int i = 0; i < 4; ++i)
#pragma unroll
        for (int j = 0; j < CPT; ++j) {
          acc[i][j][0] = fmaf(a[i].x, w0[j].x, acc[i][j][0]);
          acc[i][j][0] = fmaf(a[i].y, w0[j].y, acc[i][j][0]);
          acc[i][j][0] = fmaf(a[i].z, w0[j].z, acc[i][j][0]);
          acc[i][j][0] = fmaf(a[i].w, w0[j].w, acc[i][j][0]);
          acc[i][j][1] = fmaf(a[i].x, w1[j].x, acc[i][j][1]);
          acc[i][j][1] = fmaf(a[i].y, w1[j].y, acc[i][j][1]);
          acc[i][j][1] = fmaf(a[i].z, w1[j].z, acc[i][j][1]);
          acc[i][j][1] = fmaf(a[i].w, w1[j].w, acc[i][j][1]);
        }
    }
    __syncthreads();
  }

#pragma unroll
  for (int i = 0; i < 4; ++i) {
    const int node = n0 + tr * 4 + i;
    if (node < n) {
      if constexpr (HALF0) {
        __half* O0 = (__half*)O0v;
#pragma unroll
        for (int j = 0; j < CPT; ++j)
          O0[(size_t)node * J + tc + 32 * j] = __float2half(acc[i][j][0]);
      } else {
        float* O0 = (float*)O0v;
#pragma unroll
        for (int j = 0; j < CPT; ++j)
          O0[(size_t)node * J + tc + 32 * j] = acc[i][j][0];
      }
#pragma unroll
      for (int j = 0; j < CPT; ++j)
        O1[(size_t)node * J + tc + 32 * j] = acc[i][j][1];
    }
  }
}

// ---------------------------------------------------------------------------
// CSR build: bucket hist (LDS only) -> bucket scan -> partition ->
// per-bucket deg/row/scatter (all per-node RMW in LDS).
// ---------------------------------------------------------------------------
__launch_bounds__(256) __global__
void histB_kernel(const int* __restrict__ ei, int* __restrict__ bhist) {
  __shared__ int lb[NBKT];
  for (int i = threadIdx.x; i < NBKT; i += 256) lb[i] = 0;
  __syncthreads();
  const int e0 = blockIdx.x * 1024 + threadIdx.x;
#pragma unroll
  for (int k = 0; k < 4; ++k) {
    const int e = e0 + k * 256;
    if (e < N_EDGES) atomicAdd(&lb[ei[N_EDGES + e] >> BKT_SHIFT], 1);
  }
  __syncthreads();
  for (int i = threadIdx.x; i < NBKT; i += 256)
    if (lb[i]) atomicAdd(&bhist[i], lb[i]);
}

__launch_bounds__(256) __global__
void bscan_kernel(const int* __restrict__ bhist, int* __restrict__ bbase,
                  int* __restrict__ bcursor) {
  __shared__ int ls[256];
  const int tid = threadIdx.x;
  const int v = (tid < NBKT) ? bhist[tid] : 0;
  ls[tid] = v;
  __syncthreads();
  for (int d = 1; d < 256; d <<= 1) {
    const int t = (tid >= d) ? ls[tid - d] : 0;
    __syncthreads();
    ls[tid] += t;
    __syncthreads();
  }
  if (tid < NBKT) {
    const int ex = ls[tid] - v;
    bbase[tid] = ex;
    bcursor[tid] = ex;
  }
}

// phase A: scatter edges into bucket-contiguous staging (dense writes).
__launch_bounds__(1024) __global__
void partA_kernel(const int* __restrict__ ei, int* __restrict__ bcursor,
                  int2* __restrict__ staging) {
  __shared__ int lh[NBKT];
  __shared__ int lbase[NBKT];
  const int tid = threadIdx.x;
  for (int i = tid; i < NBKT; i += 1024) lh[i] = 0;
  __syncthreads();
  const int e0 = blockIdx.x * 4096 + tid;
  int s[4], d[4];
#pragma unroll
  for (int k = 0; k < 4; ++k) {
    const int e = e0 + k * 1024;
    const bool ok = e < N_EDGES;
    s[k] = ok ? ei[e] : 0;
    d[k] = ok ? ei[N_EDGES + e] : -1;
    if (ok) atomicAdd(&lh[d[k] >> BKT_SHIFT], 1);
  }
  __syncthreads();
  for (int i = tid; i < NBKT; i += 1024) {
    const int c = lh[i];
    lbase[i] = c ? atomicAdd(&bcursor[i], c) : 0;
    lh[i] = 0;
  }
  __syncthreads();
#pragma unroll
  for (int k = 0; k < 4; ++k) {
    if (d[k] >= 0) {
      const int b = d[k] >> BKT_SHIFT;
      const int p = lbase[b] + atomicAdd(&lh[b], 1);
      staging[p] = make_int2(s[k], d[k]);
    }
  }
}

// phase B: per-bucket deg count (LDS), 512-scan -> rowdeg, then local scatter.
__launch_bounds__(256) __global__
void partB_kernel(const int2* __restrict__ staging,
                  const int* __restrict__ bbase, const int* __restrict__ bhist,
                  int2* __restrict__ rowdeg, int* __restrict__ csr_src) {
  __shared__ int ldeg[BKT_NODES];
  __shared__ int lsc[256];
  const int b = blockIdx.x;
  const int tid = threadIdx.x;
  const int node0 = b << BKT_SHIFT;
  ldeg[2 * tid] = 0;
  ldeg[2 * tid + 1] = 0;
  __syncthreads();
  const int start = bbase[b];
  const int cnt = bhist[b];
  for (int i = tid; i < cnt; i += 256)
    atomicAdd(&ldeg[staging[start + i].y - node0], 1);
  __syncthreads();
  // 512-wide exclusive scan (2 elems/thread)
  const int d0 = ldeg[2 * tid];
  const int d1 = ldeg[2 * tid + 1];
  const int psum = d0 + d1;
  lsc[tid] = psum;
  __syncthreads();
  for (int d = 1; d < 256; d <<= 1) {
    const int t = (tid >= d) ? lsc[tid - d] : 0;
    __syncthreads();
    lsc[tid] += t;
    __syncthreads();
  }
  const int ex = lsc[tid] - psum + start;  // global CSR offset
  const int n0 = node0 + 2 * tid;
  if (n0 < N_NODES)   // N even -> n0+1 also < N
    *reinterpret_cast<int4*>(&rowdeg[n0]) = make_int4(ex, d0, ex + d0, d1);
  __syncthreads();
  // reuse ldeg as write cursor
  ldeg[2 * tid] = ex;
  ldeg[2 * tid + 1] = ex + d0;
  __syncthreads();
  for (int i = tid; i < cnt; i += 256) {
    const int2 e = staging[start + i];
    const int p = atomicAdd(&ldeg[e.y - node0], 1);
    csr_src[p] = e.x;
  }
}

// ---------------------------------------------------------------------------
// Layer 1 fused softmax-aggregate. H=2, C=32 (64 ch). One wave per node.
// v3: 4 channels/lane (2x hvec2), 16 lanes/edge, 4 edges per wave-inst.
// Score math in packed fp16 (pk_add/pk_mul/pk_max) + v_dot2_f32_f16;
// 3-level head-local butterfly; f32 accumulate (v_fma_mix).
// ---------------------------------------------------------------------------
__launch_bounds__(256) __global__
void gat1_kernel(const __half* __restrict__ xlh, const float* __restrict__ xr,
                 const float* __restrict__ att, const int2* __restrict__ rowdeg,
                 const int* __restrict__ csr_src, float* __restrict__ agg) {
  const int n =
      __builtin_amdgcn_readfirstlane(blockIdx.x * 4 + (threadIdx.x >> 6));
  if (n >= N_NODES) return;
  const int lane = threadIdx.x & 63;
  const int g = lane >> 4;  // edge subgroup 0..3
  const int m = lane & 15;  // channel slice: channels 4m..4m+3 (head = m>>3)
  const int2 rd = rowdeg[n];
  const int r0 = __builtin_amdgcn_readfirstlane(rd.x);
  const int dg = __builtin_amdgcn_readfirstlane(rd.y);

  const float4 xrf =
      *reinterpret_cast<const float4*>(xr + ((size_t)n << 6) + 4 * m);
  const hvec2 xh01 = {(_Float16)xrf.x, (_Float16)xrf.y};
  const hvec2 xh23 = {(_Float16)xrf.z, (_Float16)xrf.w};
  const float4 atf = *reinterpret_cast<const float4*>(att + 4 * m);
  const hvec2 at01 = {(_Float16)atf.x, (_Float16)atf.y};
  const hvec2 at23 = {(_Float16)atf.z, (_Float16)atf.w};

  float s = 0.f, acc0 = 0.f, acc1 = 0.f, acc2 = 0.f, acc3 = 0.f;

  // gather 4 ksteps (16 edges); lane gets 8B of xl[src] row (128B/row)
  auto issue = [&](int q0, uint2 (&dst)[4], int srcv) {
#pragma unroll
    for (int k = 0; k < 4; ++k) {
      const int sel = __shfl(srcv, 4 * (q0 + k) + g);
      dst[k] = *reinterpret_cast<const uint2*>(
          (const char*)xlh + (((size_t)(unsigned)sel) << 7) + 8 * m);
    }
  };
  auto compute = [&](int q0, uint2 (&buf)[4], int rem) {
#pragma unroll
    for (int k = 0; k < 4; ++k) {
      const hvec2 a01 = __builtin_bit_cast(hvec2, buf[k].x);
      const hvec2 a23 = __builtin_bit_cast(hvec2, buf[k].y);
      const hvec2 v01 = leaky2(a01 + xh01);
      const hvec2 v23 = leaky2(a23 + xh23);
      float p = fdot2(v23, at23, fdot2(v01, at01, 0.f));
      p += __shfl_xor(p, 1);
      p += __shfl_xor(p, 2);
      p += __shfl_xor(p, 4);  // 8-lane head-local allreduce
      float e = __expf(p);
      e = (4 * (q0 + k) + g < rem) ? e : 0.f;
      s += e;
      acc0 = fmaf(e, (float)a01.x, acc0);  // v_fma_mix
      acc1 = fmaf(e, (float)a01.y, acc1);
      acc2 = fmaf(e, (float)a23.x, acc2);
      acc3 = fmaf(e, (float)a23.y, acc3);
    }
  };

  for (int c0 = 0; c0 < dg; c0 += 64) {
    const int rem = dg - c0;
    int srcv = 0;
    if (lane < rem) srcv = csr_src[r0 + c0 + lane];  // coalesced, exec-masked
    const int Kc = (min(rem, 64) + 3) >> 2;          // ksteps (4 edges each)
    uint2 B0[4], B1[4];
    issue(0, B0, srcv);
    if (Kc > 4) issue(4, B1, srcv);
    compute(0, B0, rem);
    if (Kc > 4) {
      compute(4, B1, rem);
      if (Kc > 8) {
        issue(8, B0, srcv);
        if (Kc > 12) issue(12, B1, srcv);
        compute(8, B0, rem);
        if (Kc > 12) compute(12, B1, rem);
      }
    }
  }

  // merge the 4 edge subgroups (lane bits 4,5)
  s += __shfl_xor(s, 16);
  s += __shfl_xor(s, 32);
  acc0 += __shfl_xor(acc0, 16);
  acc0 += __shfl_xor(acc0, 32);
  acc1 += __shfl_xor(acc1, 16);
  acc1 += __shfl_xor(acc1, 32);
  acc2 += __shfl_xor(acc2, 16);
  acc2 += __shfl_xor(acc2, 32);
  acc3 += __shfl_xor(acc3, 16);
  acc3 += __shfl_xor(acc3, 32);
  const float inv = s > 0.f ? 1.f / s : 0.f;
  if (g == 0)
    *reinterpret_cast<float4*>(agg + ((size_t)n << 6) + 4 * m) =
        make_float4(acc0 * inv, acc1 * inv, acc2 * inv, acc3 * inv);
}

// ---------------------------------------------------------------------------
// Layer 2 fused: H=1, C=32. v3: 4 channels/lane, 8 lanes/edge, 8 edges per
// wave-inst; packed-fp16 score + dot2; 3-level reduce each way.
// Epilogue: bias+relu -> h2; gate matvec split across wave halves.
// ---------------------------------------------------------------------------
__launch_bounds__(256) __global__
void gat2_kernel(const __half* __restrict__ xlh, const float* __restrict__ xr,
                 const float* __restrict__ att, const int2* __restrict__ rowdeg,
                 const int* __restrict__ csr_src,
                 const float* __restrict__ b2, const float* __restrict__ g1w,
                 const float* __restrict__ g1b, const float* __restrict__ g2w,
                 const float* __restrict__ g2b, float* __restrict__ h2,
                 float* __restrict__ gate) {
  const int n =
      __builtin_amdgcn_readfirstlane(blockIdx.x * 4 + (threadIdx.x >> 6));
  if (n >= N_NODES) return;
  const int lane = threadIdx.x & 63;
  const int g = lane >> 3;  // edge subgroup 0..7
  const int m = lane & 7;   // channel slice: channels 4m..4m+3
  const int2 rd = rowdeg[n];
  const int r0 = __builtin_amdgcn_readfirstlane(rd.x);
  const int dg = __builtin_amdgcn_readfirstlane(rd.y);

  const float4 xrf =
      *reinterpret_cast<const float4*>(xr + (size_t)n * 32 + 4 * m);
  const hvec2 xh01 = {(_Float16)xrf.x, (_Float16)xrf.y};
  const hvec2 xh23 = {(_Float16)xrf.z, (_Float16)xrf.w};
  const float4 atf = *reinterpret_cast<const float4*>(att + 4 * m);
  const hvec2 at01 = {(_Float16)atf.x, (_Float16)atf.y};
  const hvec2 at23 = {(_Float16)atf.z, (_Float16)atf.w};

  float s = 0.f, acc0 = 0.f, acc1 = 0.f, acc2 = 0.f, acc3 = 0.f;

  auto issue = [&](int q0, uint2 (&dst)[4], int srcv) {
#pragma unroll
    for (int k = 0; k < 4; ++k) {
      const int sel = __shfl(srcv, 8 * (q0 + k) + g);
      dst[k] = *reinterpret_cast<const uint2*>(
          (const char*)xlh + (((size_t)(unsigned)sel) << 6) + 8 * m);
    }
  };
  auto compute = [&](int q0, uint2 (&buf)[4], int rem) {
#pragma unroll
    for (int k = 0; k < 4; ++k) {
      const hvec2 a01 = __builtin_bit_cast(hvec2, buf[k].x);
      const hvec2 a23 = __builtin_bit_cast(hvec2, buf[k].y);
      const hvec2 v01 = leaky2(a01 + xh01);
      const hvec2 v23 = leaky2(a23 + xh23);
      float p = fdot2(v23, at23, fdot2(v01, at01, 0.f));
      p += __shfl_xor(p, 1);
      p += __shfl_xor(p, 2);
      p += __shfl_xor(p, 4);  // 8-lane (full channel) allreduce
      float e = __expf(p);
      e = (8 * (q0 + k) + g < rem) ? e : 0.f;
      s += e;
      acc0 = fmaf(e, (float)a01.x, acc0);
      acc1 = fmaf(e, (float)a01.y, acc1);
      acc2 = fmaf(e, (float)a23.x, acc2);
      acc3 = fmaf(e, (float)a23.y, acc3);
    }
  };

  for (int c0 = 0; c0 < dg; c0 += 64) {
    const int rem = dg - c0;
    int srcv = 0;
    if (lane < rem) srcv = csr_src[r0 + c0 + lane];
    const int Kc = (min(rem, 64) + 7) >> 3;  // ksteps (8 edges each), 1..8
    uint2 B0[4], B1[4];
    issue(0, B0, srcv);
    if (Kc > 4) issue(4, B1, srcv);
    compute(0, B0, rem);
    if (Kc > 4) compute(4, B1, rem);
  }

  // merge the 8 edge subgroups (lane bits 3,4,5)
  s += __shfl_xor(s, 8);
  s += __shfl_xor(s, 16);
  s += __shfl_xor(s, 32);
  acc0 += __shfl_xor(acc0, 8);
  acc0 += __shfl_xor(acc0, 16);
  acc0 += __shfl_xor(acc0, 32);
  acc1 += __shfl_xor(acc1, 8);
  acc1 += __shfl_xor(acc1, 16);
  acc1 += __shfl_xor(acc1, 32);
  acc2 += __shfl_xor(acc2, 8);
  acc2 += __shfl_xor(acc2, 16);
  acc2 += __shfl_xor(acc2, 32);
  acc3 += __shfl_xor(acc3, 8);
  acc3 += __shfl_xor(acc3, 16);
  acc3 += __shfl_xor(acc3, 32);
  const float inv = s > 0.f ? 1.f / s : 0.f;
  const float4 b2v = *reinterpret_cast<const float4*>(b2 + 4 * m);
  const float h0 = fmaxf(fmaf(acc0, inv, b2v.x), 0.f);
  const float h1 = fmaxf(fmaf(acc1, inv, b2v.y), 0.f);
  const float h2v = fmaxf(fmaf(acc2, inv, b2v.z), 0.f);
  const float h3 = fmaxf(fmaf(acc3, inv, b2v.w), 0.f);
  if (g == 0)
    *reinterpret_cast<float4*>(h2 + (size_t)n * 32 + 4 * m) =
        make_float4(h0, h1, h2v, h3);

  // redistribute to 1-channel-per-lane (c = lane&31) for the gate matvec
  const int c = lane & 31;
  const float t0 = __shfl(h0, c >> 2, 8);
  const float t1 = __shfl(h1, c >> 2, 8);
  const float t2 = __shfl(h2v, c >> 2, 8);
  const float t3 = __shfl(h3, c >> 2, 8);
  const float hv = (c & 2) ? ((c & 1) ? t3 : t2) : ((c & 1) ? t1 : t0);
  // split the 32-k dot across the two 32-lane halves: 16 iters each
  const int k0 = (lane >> 5) << 4;  // 0 or 16
  float sg = 0.f;
#pragma unroll
  for (int k = 0; k < 16; ++k) {
    const int kk = k0 + k;
    sg = fmaf(__shfl(hv, kk, 32), g1w[kk * 32 + c], sg);
  }
  sg += __shfl_xor(sg, 32);  // merge halves
  sg = fmaxf(sg + g1b[c], 0.f);
  float pg = sg * g2w[c];
  pg += __shfl_xor(pg, 1);
  pg += __shfl_xor(pg, 2);
  pg += __shfl_xor(pg, 4);
  pg += __shfl_xor(pg, 8);
  pg += __shfl_xor(pg, 16);
  if (lane == 0) gate[n] = pg + g2b[0];
}

// ---------------------------------------------------------------------------
__launch_bounds__(256) __global__
void gepool_kernel(const float* __restrict__ h2, const int* __restrict__ batch,
                   const float* __restrict__ gate, float* __restrict__ gd,
                   float* __restrict__ pooled) {
  __shared__ float pool[G_GRAPHS * 32];
  __shared__ float gdb[G_GRAPHS];
  const int tid = threadIdx.x;
  for (int i = tid; i < G_GRAPHS * 32; i += 256) pool[i] = 0.f;
  if (tid < G_GRAPHS) gdb[tid] = 0.f;
  __syncthreads();
  const int c = tid & 31;
  const int hw = tid >> 5;
  const int start = blockIdx.x * 256;
  const int end = min(N_NODES, start + 256);
  for (int n = start + hw; n < end; n += 8) {
    const int b = batch[n];
    const float ge = __expf(gate[n]);
    atomicAdd(&pool[b * 32 + c], ge * h2[(size_t)n * 32 + c]);
    if (c == 0) atomicAdd(&gdb[b], ge);
  }
  __syncthreads();
  for (int i = tid; i < G_GRAPHS * 32; i += 256)
    if (pool[i] != 0.f) unsafeAtomicAdd(&pooled[i], pool[i]);
  if (tid < G_GRAPHS && gdb[tid] != 0.f) unsafeAtomicAdd(&gd[tid], gdb[tid]);
}

__launch_bounds__(64) __global__
void final_kernel(const float* __restrict__ pooled, const float* __restrict__ gd,
                  const float* __restrict__ l1w, const float* __restrict__ l1b,
                  const float* __restrict__ l2w, const float* __restrict__ l2b,
                  float* __restrict__ out) {
  const int g = blockIdx.x;
  const int lane = threadIdx.x;
  if (lane >= 32) return;
  const float invgd = 1.f / gd[g];
  float s = l1b[lane];
#pragma unroll
  for (int k = 0; k < 32; ++k)
    s = fmaf(pooled[g * 32 + k] * invgd, l1w[k * 32 + lane], s);
  s = fmaxf(s, 0.f);
  float p = s * l2w[lane];
  p += __shfl_xor(p, 1);
  p += __shfl_xor(p, 2);
  p += __shfl_xor(p, 4);
  p += __shfl_xor(p, 8);
  p += __shfl_xor(p, 16);
  if (lane == 0) out[g] = p + l2b[0];
}

// ---------------------------------------------------------------------------
extern "C" void kernel_launch(void* const* d_in, const int* in_sizes, int n_in,
                              void* d_out, int out_size, void* d_ws,
                              size_t ws_size, hipStream_t stream) {
  const float* x    = (const float*)d_in[0];
  const int*   ei   = (const int*)d_in[1];
  const int*   batch= (const int*)d_in[2];
  const float* Wl1  = (const float*)d_in[3];
  const float* Wr1  = (const float*)d_in[4];
  const float* att1 = (const float*)d_in[5];
  const float* b1   = (const float*)d_in[6];
  const float* Wl2  = (const float*)d_in[7];
  const float* Wr2  = (const float*)d_in[8];
  const float* att2 = (const float*)d_in[9];
  const float* b2   = (const float*)d_in[10];
  const float* g1w  = (const float*)d_in[11];
  const float* g1b  = (const float*)d_in[12];
  const float* g2w  = (const float*)d_in[13];
  const float* g2b  = (const float*)d_in[14];
  const float* l1w  = (const float*)d_in[15];
  const float* l1b  = (const float*)d_in[16];
  const float* l2w  = (const float*)d_in[17];
  const float* l2b  = (const float*)d_in[18];
  float* out = (float*)d_out;

  // ---- workspace layout ----
  int* bhist   = (int*)d_ws;            // NBKT (zeroed)
  int* bbase   = bhist + NBKT;          // NBKT
  int* bcursor = bbase + NBKT;          // NBKT
  int2* rowdeg = (int2*)(bcursor + NBKT);            // N int2 {row, deg}
  int* csr_src = (int*)(rowdeg + N_NODES);           // E + 16 pad
  int2* staging = (int2*)(csr_src + N_EDGES + 16);   // E int2
  float* fbase = (float*)(staging + N_EDGES);
  float* xr1  = fbase;                         // N*64
  float* agg1 = xr1 + (size_t)N_NODES * 64;    // N*64
  float* gate = agg1 + (size_t)N_NODES * 64;   // N
  float* gd   = gate + N_NODES;                // 64
  float* pooled = gd + G_GRAPHS;               // 64*32
  __half* xl1h = (__half*)(pooled + G_GRAPHS * 32);  // N*64 half
  // layer-2 aliases (stream-ordered producers/consumers)
  __half* xl2h = xl1h;                         // N*32 half
  float* xr2 = xr1;                            // N*32 (first half of xr1)
  float* h2  = xr1 + (size_t)N_NODES * 32;     // N*32 (second half of xr1)

  (void)hipMemsetAsync(bhist, 0, (size_t)NBKT * sizeof(int), stream);
  (void)hipMemsetAsync(gd, 0,
                       (size_t)(G_GRAPHS + G_GRAPHS * 32) * sizeof(float),
                       stream);

  // CSR build: bucket hist -> scan -> partition -> per-bucket deg/row/scatter
  histB_kernel<<<(N_EDGES + 1023) / 1024, 256, 0, stream>>>(ei, bhist);
  bscan_kernel<<<1, 256, 0, stream>>>(bhist, bbase, bcursor);
  partA_kernel<<<(N_EDGES + 4095) / 4096, 1024, 0, stream>>>(ei, bcursor,
                                                             staging);
  partB_kernel<<<NBKT, 256, 0, stream>>>(staging, bbase, bhist, rowdeg,
                                         csr_src);

  // Layer 1 (xl staged fp16)
  gemm_dual<128, 64, false, true><<<(N_NODES + 31) / 32, 256, 0, stream>>>(
      x, Wl1, Wr1, nullptr, (void*)xl1h, xr1, N_NODES);
  gat1_kernel<<<(N_NODES + 3) / 4, 256, 0, stream>>>(xl1h, xr1, att1, rowdeg,
                                                     csr_src, agg1);

  // Layer 2 (bias1+relu fused into A-load; gate fused into epilogue)
  gemm_dual<64, 32, true, true><<<(N_NODES + 31) / 32, 256, 0, stream>>>(
      agg1, Wl2, Wr2, b1, (void*)xl2h, xr2, N_NODES);
  gat2_kernel<<<(N_NODES + 3) / 4, 256, 0, stream>>>(
      xl2h, xr2, att2, rowdeg, csr_src, b2, g1w, g1b, g2w, g2b, h2, gate);

  // Pooling + head (no-max graph softmax)
  gepool_kernel<<<(N_NODES + 255) / 256, 256, 0, stream>>>(h2, batch, gate, gd,
                                                           pooled);
  final_kernel<<<64, 64, 0, stream>>>(pooled, gd, l1w, l1b, l2w, l2b, out);
}

// Round 5
// 411.134 us; speedup vs baseline: 1.0769x; 1.0291x over previous
//
#include <hip/hip_runtime.h>
#include <hip/hip_fp16.h>
#include <cfloat>
#include <cstdint>
#include <cstddef>

#define N_NODES 100000
#define N_EDGES 1600000
#define G_GRAPHS 64
#define BKT_SHIFT 9
#define BKT_NODES (1 << BKT_SHIFT)                              // 512
#define NBKT ((N_NODES + BKT_NODES - 1) >> BKT_SHIFT)           // 196

typedef _Float16 hvec2 __attribute__((ext_vector_type(2)));

// v_dot2_f32_f16: p = a.x*b.x + a.y*b.y + c (f32 accumulate)
static __device__ __forceinline__ float fdot2(hvec2 a, hvec2 b, float c) {
#if __has_builtin(__builtin_amdgcn_fdot2)
  return __builtin_amdgcn_fdot2(a, b, c, false);
#else
  return fmaf((float)a.y, (float)b.y, fmaf((float)a.x, (float)b.x, c));
#endif
}

// packed leaky-relu: max(v, 0.2*v)  (v_pk_mul_f16 + v_pk_max_f16)
static __device__ __forceinline__ hvec2 leaky2(hvec2 v) {
  return __builtin_elementwise_max(v, v * (_Float16)0.2f);
}

// ---------------------------------------------------------------------------
// Dual GEMM, single-pass: O0 = act(A)@W0 (fp16 if HALF0), O1 = act(A)@W1.
// ---------------------------------------------------------------------------
template <int K, int J, bool FUSE, bool HALF0>
__launch_bounds__(256) __global__
void gemm_dual(const float* __restrict__ A, const float* __restrict__ W0,
               const float* __restrict__ W1, const float* __restrict__ bias,
               void* __restrict__ O0v, float* __restrict__ O1, int n) {
  constexpr int BK = 64;
  constexpr int CPT = J / 32;
  __shared__ __align__(16) float As[32][BK];
  __shared__ __align__(16) float W0t[J][BK + 4];
  __shared__ __align__(16) float W1t[J][BK + 4];
  const int tid = threadIdx.x;
  const int n0 = blockIdx.x * 32;
  const int tr = tid >> 5;
  const int tc = tid & 31;

  float acc[4][CPT][2];
#pragma unroll
  for (int i = 0; i < 4; ++i)
#pragma unroll
    for (int j = 0; j < CPT; ++j) {
      acc[i][j][0] = 0.f;
      acc[i][j][1] = 0.f;
    }

  for (int kc = 0; kc < K; kc += BK) {
    for (int i = tid; i < 32 * BK / 4; i += 256) {
      const int node = i / (BK / 4);
      const int kg = i % (BK / 4);
      float4 v = make_float4(0.f, 0.f, 0.f, 0.f);
      if (n0 + node < n) {
        v = reinterpret_cast<const float4*>(
            A)[(size_t)(n0 + node) * (K / 4) + kc / 4 + kg];
        if constexpr (FUSE) {
          const float4 b =
              reinterpret_cast<const float4*>(bias)[kc / 4 + kg];
          v.x = fmaxf(v.x + b.x, 0.f);
          v.y = fmaxf(v.y + b.y, 0.f);
          v.z = fmaxf(v.z + b.z, 0.f);
          v.w = fmaxf(v.w + b.w, 0.f);
        }
      }
      reinterpret_cast<float4*>(&As[node][0])[kg] = v;
    }
    for (int i = tid; i < BK * J; i += 256) {
      const int k = i / J;
      const int j = i % J;
      W0t[j][k] = W0[(size_t)(kc + k) * J + j];
      W1t[j][k] = W1[(size_t)(kc + k) * J + j];
    }
    __syncthreads();

#pragma unroll 2
    for (int k4 = 0; k4 < BK / 4; ++k4) {
      float4 a[4];
#pragma unroll
      for (int i = 0; i < 4; ++i)
        a[i] = reinterpret_cast<const float4*>(&As[tr * 4 + i][0])[k4];
      float4 w0[CPT], w1[CPT];
#pragma unroll
      for (int j = 0; j < CPT; ++j) {
        w0[j] = *reinterpret_cast<const float4*>(&W0t[tc + 32 * j][k4 * 4]);
        w1[j] = *reinterpret_cast<const float4*>(&W1t[tc + 32 * j][k4 * 4]);
      }
#pragma unroll
      for (int i = 0; i < 4; ++i)
#pragma unroll
        for (int j = 0; j < CPT; ++j) {
          acc[i][j][0] = fmaf(a[i].x, w0[j].x, acc[i][j][0]);
          acc[i][j][0] = fmaf(a[i].y, w0[j].y, acc[i][j][0]);
          acc[i][j][0] = fmaf(a[i].z, w0[j].z, acc[i][j][0]);
          acc[i][j][0] = fmaf(a[i].w, w0[j].w, acc[i][j][0]);
          acc[i][j][1] = fmaf(a[i].x, w1[j].x, acc[i][j][1]);
          acc[i][j][1] = fmaf(a[i].y, w1[j].y, acc[i][j][1]);
          acc[i][j][1] = fmaf(a[i].z, w1[j].z, acc[i][j][1]);
          acc[i][j][1] = fmaf(a[i].w, w1[j].w, acc[i][j][1]);
        }
    }
    __syncthreads();
  }

#pragma unroll
  for (int i = 0; i < 4; ++i) {
    const int node = n0 + tr * 4 + i;
    if (node < n) {
      if constexpr (HALF0) {
        __half* O0 = (__half*)O0v;
#pragma unroll
        for (int j = 0; j < CPT; ++j)
          O0[(size_t)node * J + tc + 32 * j] = __float2half(acc[i][j][0]);
      } else {
        float* O0 = (float*)O0v;
#pragma unroll
        for (int j = 0; j < CPT; ++j)
          O0[(size_t)node * J + tc + 32 * j] = acc[i][j][0];
      }
#pragma unroll
      for (int j = 0; j < CPT; ++j)
        O1[(size_t)node * J + tc + 32 * j] = acc[i][j][1];
    }
  }
}

// ---------------------------------------------------------------------------
// CSR build: bucket hist (LDS only) -> bucket scan -> partition ->
// per-bucket deg/row/scatter (all per-node RMW in LDS).
// ---------------------------------------------------------------------------
__launch_bounds__(256) __global__
void histB_kernel(const int* __restrict__ ei, int* __restrict__ bhist) {
  __shared__ int lb[NBKT];
  for (int i = threadIdx.x; i < NBKT; i += 256) lb[i] = 0;
  __syncthreads();
  const int e0 = blockIdx.x * 1024 + threadIdx.x;
#pragma unroll
  for (int k = 0; k < 4; ++k) {
    const int e = e0 + k * 256;
    if (e < N_EDGES) atomicAdd(&lb[ei[N_EDGES + e] >> BKT_SHIFT], 1);
  }
  __syncthreads();
  for (int i = threadIdx.x; i < NBKT; i += 256)
    if (lb[i]) atomicAdd(&bhist[i], lb[i]);
}

__launch_bounds__(256) __global__
void bscan_kernel(const int* __restrict__ bhist, int* __restrict__ bbase,
                  int* __restrict__ bcursor) {
  __shared__ int ls[256];
  const int tid = threadIdx.x;
  const int v = (tid < NBKT) ? bhist[tid] : 0;
  ls[tid] = v;
  __syncthreads();
  for (int d = 1; d < 256; d <<= 1) {
    const int t = (tid >= d) ? ls[tid - d] : 0;
    __syncthreads();
    ls[tid] += t;
    __syncthreads();
  }
  if (tid < NBKT) {
    const int ex = ls[tid] - v;
    bbase[tid] = ex;
    bcursor[tid] = ex;
  }
}

// phase A: scatter edges into bucket-contiguous staging (dense writes).
__launch_bounds__(1024) __global__
void partA_kernel(const int* __restrict__ ei, int* __restrict__ bcursor,
                  int2* __restrict__ staging) {
  __shared__ int lh[NBKT];
  __shared__ int lbase[NBKT];
  const int tid = threadIdx.x;
  for (int i = tid; i < NBKT; i += 1024) lh[i] = 0;
  __syncthreads();
  const int e0 = blockIdx.x * 4096 + tid;
  int s[4], d[4];
#pragma unroll
  for (int k = 0; k < 4; ++k) {
    const int e = e0 + k * 1024;
    const bool ok = e < N_EDGES;
    s[k] = ok ? ei[e] : 0;
    d[k] = ok ? ei[N_EDGES + e] : -1;
    if (ok) atomicAdd(&lh[d[k] >> BKT_SHIFT], 1);
  }
  __syncthreads();
  for (int i = tid; i < NBKT; i += 1024) {
    const int c = lh[i];
    lbase[i] = c ? atomicAdd(&bcursor[i], c) : 0;
    lh[i] = 0;
  }
  __syncthreads();
#pragma unroll
  for (int k = 0; k < 4; ++k) {
    if (d[k] >= 0) {
      const int b = d[k] >> BKT_SHIFT;
      const int p = lbase[b] + atomicAdd(&lh[b], 1);
      staging[p] = make_int2(s[k], d[k]);
    }
  }
}

// phase B: per-bucket deg count (LDS), 512-scan -> rowdeg, then local scatter.
__launch_bounds__(256) __global__
void partB_kernel(const int2* __restrict__ staging,
                  const int* __restrict__ bbase, const int* __restrict__ bhist,
                  int2* __restrict__ rowdeg, int* __restrict__ csr_src) {
  __shared__ int ldeg[BKT_NODES];
  __shared__ int lsc[256];
  const int b = blockIdx.x;
  const int tid = threadIdx.x;
  const int node0 = b << BKT_SHIFT;
  ldeg[2 * tid] = 0;
  ldeg[2 * tid + 1] = 0;
  __syncthreads();
  const int start = bbase[b];
  const int cnt = bhist[b];
  for (int i = tid; i < cnt; i += 256)
    atomicAdd(&ldeg[staging[start + i].y - node0], 1);
  __syncthreads();
  // 512-wide exclusive scan (2 elems/thread)
  const int d0 = ldeg[2 * tid];
  const int d1 = ldeg[2 * tid + 1];
  const int psum = d0 + d1;
  lsc[tid] = psum;
  __syncthreads();
  for (int d = 1; d < 256; d <<= 1) {
    const int t = (tid >= d) ? lsc[tid - d] : 0;
    __syncthreads();
    lsc[tid] += t;
    __syncthreads();
  }
  const int ex = lsc[tid] - psum + start;  // global CSR offset
  const int n0 = node0 + 2 * tid;
  if (n0 < N_NODES)   // N even -> n0+1 also < N
    *reinterpret_cast<int4*>(&rowdeg[n0]) = make_int4(ex, d0, ex + d0, d1);
  __syncthreads();
  // reuse ldeg as write cursor
  ldeg[2 * tid] = ex;
  ldeg[2 * tid + 1] = ex + d0;
  __syncthreads();
  for (int i = tid; i < cnt; i += 256) {
    const int2 e = staging[start + i];
    const int p = atomicAdd(&ldeg[e.y - node0], 1);
    csr_src[p] = e.x;
  }
}

// ---------------------------------------------------------------------------
// Layer 1 fused softmax-aggregate. H=2, C=32 (64 ch). One wave per node.
// v5: packed-fp16 math (v4) + kstep-granularity wave-uniform guards: only
// ceil(deg/4) ksteps execute (was ceil(deg/16)*4) -> no padded slots.
// ---------------------------------------------------------------------------
__launch_bounds__(256) __global__
void gat1_kernel(const __half* __restrict__ xlh, const float* __restrict__ xr,
                 const float* __restrict__ att, const int2* __restrict__ rowdeg,
                 const int* __restrict__ csr_src, float* __restrict__ agg) {
  const int n =
      __builtin_amdgcn_readfirstlane(blockIdx.x * 4 + (threadIdx.x >> 6));
  if (n >= N_NODES) return;
  const int lane = threadIdx.x & 63;
  const int g = lane >> 4;  // edge subgroup 0..3
  const int m = lane & 15;  // channel slice: channels 4m..4m+3 (head = m>>3)
  const int2 rd = rowdeg[n];
  const int r0 = __builtin_amdgcn_readfirstlane(rd.x);
  const int dg = __builtin_amdgcn_readfirstlane(rd.y);

  const float4 xrf =
      *reinterpret_cast<const float4*>(xr + ((size_t)n << 6) + 4 * m);
  const hvec2 xh01 = {(_Float16)xrf.x, (_Float16)xrf.y};
  const hvec2 xh23 = {(_Float16)xrf.z, (_Float16)xrf.w};
  const float4 atf = *reinterpret_cast<const float4*>(att + 4 * m);
  const hvec2 at01 = {(_Float16)atf.x, (_Float16)atf.y};
  const hvec2 at23 = {(_Float16)atf.z, (_Float16)atf.w};

  float s = 0.f, acc0 = 0.f, acc1 = 0.f, acc2 = 0.f, acc3 = 0.f;

  // one kstep = 4 edges (4*q+g); lane gets 8B of xl[src] row (128B/row)
  auto gather1 = [&](int q, int srcv) -> uint2 {
    const int sel = __shfl(srcv, 4 * q + g);
    return *reinterpret_cast<const uint2*>(
        (const char*)xlh + (((size_t)(unsigned)sel) << 7) + 8 * m);
  };
  auto compute1 = [&](int q, uint2 buf, int rem) {
    const hvec2 a01 = __builtin_bit_cast(hvec2, buf.x);
    const hvec2 a23 = __builtin_bit_cast(hvec2, buf.y);
    const hvec2 v01 = leaky2(a01 + xh01);
    const hvec2 v23 = leaky2(a23 + xh23);
    float p = fdot2(v23, at23, fdot2(v01, at01, 0.f));
    p += __shfl_xor(p, 1);
    p += __shfl_xor(p, 2);
    p += __shfl_xor(p, 4);  // 8-lane head-local allreduce
    float e = __expf(p);
    e = (4 * q + g < rem) ? e : 0.f;
    s += e;
    acc0 = fmaf(e, (float)a01.x, acc0);  // v_fma_mix
    acc1 = fmaf(e, (float)a01.y, acc1);
    acc2 = fmaf(e, (float)a23.x, acc2);
    acc3 = fmaf(e, (float)a23.y, acc3);
  };

  for (int c0 = 0; c0 < dg; c0 += 64) {
    const int rem = dg - c0;
    int srcv = 0;
    if (lane < rem) srcv = csr_src[r0 + c0 + lane];  // coalesced, exec-masked
    const int Kc = (min(rem, 64) + 3) >> 2;          // 1..16 ksteps
#pragma unroll
    for (int g0 = 0; g0 < 16; g0 += 4) {
      if (g0 < Kc) {  // wave-uniform (scalar branch)
        uint2 B[4];
#pragma unroll
        for (int k = 0; k < 4; ++k)
          if (g0 + k < Kc) B[k] = gather1(g0 + k, srcv);
#pragma unroll
        for (int k = 0; k < 4; ++k)
          if (g0 + k < Kc) compute1(g0 + k, B[k], rem);
      }
    }
  }

  // merge the 4 edge subgroups (lane bits 4,5)
  s += __shfl_xor(s, 16);
  s += __shfl_xor(s, 32);
  acc0 += __shfl_xor(acc0, 16);
  acc0 += __shfl_xor(acc0, 32);
  acc1 += __shfl_xor(acc1, 16);
  acc1 += __shfl_xor(acc1, 32);
  acc2 += __shfl_xor(acc2, 16);
  acc2 += __shfl_xor(acc2, 32);
  acc3 += __shfl_xor(acc3, 16);
  acc3 += __shfl_xor(acc3, 32);
  const float inv = s > 0.f ? 1.f / s : 0.f;
  if (g == 0)
    *reinterpret_cast<float4*>(agg + ((size_t)n << 6) + 4 * m) =
        make_float4(acc0 * inv, acc1 * inv, acc2 * inv, acc3 * inv);
}

// ---------------------------------------------------------------------------
// Layer 2 fused: H=1, C=32. v5: packed-fp16 + kstep guards (8 edges/kstep,
// only ceil(deg/8) execute). Epilogue: bias+relu -> h2; gate matvec split
// across wave halves.
// ---------------------------------------------------------------------------
__launch_bounds__(256) __global__
void gat2_kernel(const __half* __restrict__ xlh, const float* __restrict__ xr,
                 const float* __restrict__ att, const int2* __restrict__ rowdeg,
                 const int* __restrict__ csr_src,
                 const float* __restrict__ b2, const float* __restrict__ g1w,
                 const float* __restrict__ g1b, const float* __restrict__ g2w,
                 const float* __restrict__ g2b, float* __restrict__ h2,
                 float* __restrict__ gate) {
  const int n =
      __builtin_amdgcn_readfirstlane(blockIdx.x * 4 + (threadIdx.x >> 6));
  if (n >= N_NODES) return;
  const int lane = threadIdx.x & 63;
  const int g = lane >> 3;  // edge subgroup 0..7
  const int m = lane & 7;   // channel slice: channels 4m..4m+3
  const int2 rd = rowdeg[n];
  const int r0 = __builtin_amdgcn_readfirstlane(rd.x);
  const int dg = __builtin_amdgcn_readfirstlane(rd.y);

  const float4 xrf =
      *reinterpret_cast<const float4*>(xr + (size_t)n * 32 + 4 * m);
  const hvec2 xh01 = {(_Float16)xrf.x, (_Float16)xrf.y};
  const hvec2 xh23 = {(_Float16)xrf.z, (_Float16)xrf.w};
  const float4 atf = *reinterpret_cast<const float4*>(att + 4 * m);
  const hvec2 at01 = {(_Float16)atf.x, (_Float16)atf.y};
  const hvec2 at23 = {(_Float16)atf.z, (_Float16)atf.w};

  float s = 0.f, acc0 = 0.f, acc1 = 0.f, acc2 = 0.f, acc3 = 0.f;

  // one kstep = 8 edges (8*q+g); lane gets 8B of xl[src] row (64B/row)
  auto gather1 = [&](int q, int srcv) -> uint2 {
    const int sel = __shfl(srcv, 8 * q + g);
    return *reinterpret_cast<const uint2*>(
        (const char*)xlh + (((size_t)(unsigned)sel) << 6) + 8 * m);
  };
  auto compute1 = [&](int q, uint2 buf, int rem) {
    const hvec2 a01 = __builtin_bit_cast(hvec2, buf.x);
    const hvec2 a23 = __builtin_bit_cast(hvec2, buf.y);
    const hvec2 v01 = leaky2(a01 + xh01);
    const hvec2 v23 = leaky2(a23 + xh23);
    float p = fdot2(v23, at23, fdot2(v01, at01, 0.f));
    p += __shfl_xor(p, 1);
    p += __shfl_xor(p, 2);
    p += __shfl_xor(p, 4);  // 8-lane (full channel) allreduce
    float e = __expf(p);
    e = (8 * q + g < rem) ? e : 0.f;
    s += e;
    acc0 = fmaf(e, (float)a01.x, acc0);
    acc1 = fmaf(e, (float)a01.y, acc1);
    acc2 = fmaf(e, (float)a23.x, acc2);
    acc3 = fmaf(e, (float)a23.y, acc3);
  };

  for (int c0 = 0; c0 < dg; c0 += 64) {
    const int rem = dg - c0;
    int srcv = 0;
    if (lane < rem) srcv = csr_src[r0 + c0 + lane];
    const int Kc = (min(rem, 64) + 7) >> 3;  // 1..8 ksteps
#pragma unroll
    for (int g0 = 0; g0 < 8; g0 += 4) {
      if (g0 < Kc) {  // wave-uniform
        uint2 B[4];
#pragma unroll
        for (int k = 0; k < 4; ++k)
          if (g0 + k < Kc) B[k] = gather1(g0 + k, srcv);
#pragma unroll
        for (int k = 0; k < 4; ++k)
          if (g0 + k < Kc) compute1(g0 + k, B[k], rem);
      }
    }
  }

  // merge the 8 edge subgroups (lane bits 3,4,5)
  s += __shfl_xor(s, 8);
  s += __shfl_xor(s, 16);
  s += __shfl_xor(s, 32);
  acc0 += __shfl_xor(acc0, 8);
  acc0 += __shfl_xor(acc0, 16);
  acc0 += __shfl_xor(acc0, 32);
  acc1 += __shfl_xor(acc1, 8);
  acc1 += __shfl_xor(acc1, 16);
  acc1 += __shfl_xor(acc1, 32);
  acc2 += __shfl_xor(acc2, 8);
  acc2 += __shfl_xor(acc2, 16);
  acc2 += __shfl_xor(acc2, 32);
  acc3 += __shfl_xor(acc3, 8);
  acc3 += __shfl_xor(acc3, 16);
  acc3 += __shfl_xor(acc3, 32);
  const float inv = s > 0.f ? 1.f / s : 0.f;
  const float4 b2v = *reinterpret_cast<const float4*>(b2 + 4 * m);
  const float h0 = fmaxf(fmaf(acc0, inv, b2v.x), 0.f);
  const float h1 = fmaxf(fmaf(acc1, inv, b2v.y), 0.f);
  const float h2v = fmaxf(fmaf(acc2, inv, b2v.z), 0.f);
  const float h3 = fmaxf(fmaf(acc3, inv, b2v.w), 0.f);
  if (g == 0)
    *reinterpret_cast<float4*>(h2 + (size_t)n * 32 + 4 * m) =
        make_float4(h0, h1, h2v, h3);

  // redistribute to 1-channel-per-lane (c = lane&31) for the gate matvec
  const int c = lane & 31;
  const float t0 = __shfl(h0, c >> 2, 8);
  const float t1 = __shfl(h1, c >> 2, 8);
  const float t2 = __shfl(h2v, c >> 2, 8);
  const float t3 = __shfl(h3, c >> 2, 8);
  const float hv = (c & 2) ? ((c & 1) ? t3 : t2) : ((c & 1) ? t1 : t0);
  // split the 32-k dot across the two 32-lane halves: 16 iters each
  const int k0 = (lane >> 5) << 4;  // 0 or 16
  float sg = 0.f;
#pragma unroll
  for (int k = 0; k < 16; ++k) {
    const int kk = k0 + k;
    sg = fmaf(__shfl(hv, kk, 32), g1w[kk * 32 + c], sg);
  }
  sg += __shfl_xor(sg, 32);  // merge halves
  sg = fmaxf(sg + g1b[c], 0.f);
  float pg = sg * g2w[c];
  pg += __shfl_xor(pg, 1);
  pg += __shfl_xor(pg, 2);
  pg += __shfl_xor(pg, 4);
  pg += __shfl_xor(pg, 8);
  pg += __shfl_xor(pg, 16);
  if (lane == 0) gate[n] = pg + g2b[0];
}

// ---------------------------------------------------------------------------
__launch_bounds__(256) __global__
void gepool_kernel(const float* __restrict__ h2, const int* __restrict__ batch,
                   const float* __restrict__ gate, float* __restrict__ gd,
                   float* __restrict__ pooled) {
  __shared__ float pool[G_GRAPHS * 32];
  __shared__ float gdb[G_GRAPHS];
  const int tid = threadIdx.x;
  for (int i = tid; i < G_GRAPHS * 32; i += 256) pool[i] = 0.f;
  if (tid < G_GRAPHS) gdb[tid] = 0.f;
  __syncthreads();
  const int c = tid & 31;
  const int hw = tid >> 5;
  const int start = blockIdx.x * 256;
  const int end = min(N_NODES, start + 256);
  for (int n = start + hw; n < end; n += 8) {
    const int b = batch[n];
    const float ge = __expf(gate[n]);
    atomicAdd(&pool[b * 32 + c], ge * h2[(size_t)n * 32 + c]);
    if (c == 0) atomicAdd(&gdb[b], ge);
  }
  __syncthreads();
  for (int i = tid; i < G_GRAPHS * 32; i += 256)
    if (pool[i] != 0.f) unsafeAtomicAdd(&pooled[i], pool[i]);
  if (tid < G_GRAPHS && gdb[tid] != 0.f) unsafeAtomicAdd(&gd[tid], gdb[tid]);
}

__launch_bounds__(64) __global__
void final_kernel(const float* __restrict__ pooled, const float* __restrict__ gd,
                  const float* __restrict__ l1w, const float* __restrict__ l1b,
                  const float* __restrict__ l2w, const float* __restrict__ l2b,
                  float* __restrict__ out) {
  const int g = blockIdx.x;
  const int lane = threadIdx.x;
  if (lane >= 32) return;
  const float invgd = 1.f / gd[g];
  float s = l1b[lane];
#pragma unroll
  for (int k = 0; k < 32; ++k)
    s = fmaf(pooled[g * 32 + k] * invgd, l1w[k * 32 + lane], s);
  s = fmaxf(s, 0.f);
  float p = s * l2w[lane];
  p += __shfl_xor(p, 1);
  p += __shfl_xor(p, 2);
  p += __shfl_xor(p, 4);
  p += __shfl_xor(p, 8);
  p += __shfl_xor(p, 16);
  if (lane == 0) out[g] = p + l2b[0];
}

// ---------------------------------------------------------------------------
extern "C" void kernel_launch(void* const* d_in, const int* in_sizes, int n_in,
                              void* d_out, int out_size, void* d_ws,
                              size_t ws_size, hipStream_t stream) {
  const float* x    = (const float*)d_in[0];
  const int*   ei   = (const int*)d_in[1];
  const int*   batch= (const int*)d_in[2];
  const float* Wl1  = (const float*)d_in[3];
  const float* Wr1  = (const float*)d_in[4];
  const float* att1 = (const float*)d_in[5];
  const float* b1   = (const float*)d_in[6];
  const float* Wl2  = (const float*)d_in[7];
  const float* Wr2  = (const float*)d_in[8];
  const float* att2 = (const float*)d_in[9];
  const float* b2   = (const float*)d_in[10];
  const float* g1w  = (const float*)d_in[11];
  const float* g1b  = (const float*)d_in[12];
  const float* g2w  = (const float*)d_in[13];
  const float* g2b  = (const float*)d_in[14];
  const float* l1w  = (const float*)d_in[15];
  const float* l1b  = (const float*)d_in[16];
  const float* l2w  = (const float*)d_in[17];
  const float* l2b  = (const float*)d_in[18];
  float* out = (float*)d_out;

  // ---- workspace layout ----
  int* bhist   = (int*)d_ws;            // NBKT (zeroed)
  int* bbase   = bhist + NBKT;          // NBKT
  int* bcursor = bbase + NBKT;          // NBKT
  int2* rowdeg = (int2*)(bcursor + NBKT);            // N int2 {row, deg}
  int* csr_src = (int*)(rowdeg + N_NODES);           // E + 16 pad
  int2* staging = (int2*)(csr_src + N_EDGES + 16);   // E int2
  float* fbase = (float*)(staging + N_EDGES);
  float* xr1  = fbase;                         // N*64
  float* agg1 = xr1 + (size_t)N_NODES * 64;    // N*64
  float* gate = agg1 + (size_t)N_NODES * 64;   // N
  float* gd   = gate + N_NODES;                // 64
  float* pooled = gd + G_GRAPHS;               // 64*32
  __half* xl1h = (__half*)(pooled + G_GRAPHS * 32);  // N*64 half
  // layer-2 aliases (stream-ordered producers/consumers)
  __half* xl2h = xl1h;                         // N*32 half
  float* xr2 = xr1;                            // N*32 (first half of xr1)
  float* h2  = xr1 + (size_t)N_NODES * 32;     // N*32 (second half of xr1)

  (void)hipMemsetAsync(bhist, 0, (size_t)NBKT * sizeof(int), stream);
  (void)hipMemsetAsync(gd, 0,
                       (size_t)(G_GRAPHS + G_GRAPHS * 32) * sizeof(float),
                       stream);

  // CSR build: bucket hist -> scan -> partition -> per-bucket deg/row/scatter
  histB_kernel<<<(N_EDGES + 1023) / 1024, 256, 0, stream>>>(ei, bhist);
  bscan_kernel<<<1, 256, 0, stream>>>(bhist, bbase, bcursor);
  partA_kernel<<<(N_EDGES + 4095) / 4096, 1024, 0, stream>>>(ei, bcursor,
                                                             staging);
  partB_kernel<<<NBKT, 256, 0, stream>>>(staging, bbase, bhist, rowdeg,
                                         csr_src);

  // Layer 1 (xl staged fp16)
  gemm_dual<128, 64, false, true><<<(N_NODES + 31) / 32, 256, 0, stream>>>(
      x, Wl1, Wr1, nullptr, (void*)xl1h, xr1, N_NODES);
  gat1_kernel<<<(N_NODES + 3) / 4, 256, 0, stream>>>(xl1h, xr1, att1, rowdeg,
                                                     csr_src, agg1);

  // Layer 2 (bias1+relu fused into A-load; gate fused into epilogue)
  gemm_dual<64, 32, true, true><<<(N_NODES + 31) / 32, 256, 0, stream>>>(
      agg1, Wl2, Wr2, b1, (void*)xl2h, xr2, N_NODES);
  gat2_kernel<<<(N_NODES + 3) / 4, 256, 0, stream>>>(
      xl2h, xr2, att2, rowdeg, csr_src, b2, g1w, g1b, g2w, g2b, h2, gate);

  // Pooling + head (no-max graph softmax)
  gepool_kernel<<<(N_NODES + 255) / 256, 256, 0, stream>>>(h2, batch, gate, gd,
                                                           pooled);
  final_kernel<<<64, 64, 0, stream>>>(pooled, gd, l1w, l1b, l2w, l2b, out);
}

// Round 6
// 373.762 us; speedup vs baseline: 1.1846x; 1.1000x over previous
//
#include <hip/hip_runtime.h>
#include <hip/hip_fp16.h>
#include <cfloat>
#include <cstdint>
#include <cstddef>

#define N_NODES 100000
#define N_EDGES 1600000
#define G_GRAPHS 64
#define BKT_SHIFT 9
#define BKT_NODES (1 << BKT_SHIFT)                              // 512
#define NBKT ((N_NODES + BKT_NODES - 1) >> BKT_SHIFT)           // 196

typedef _Float16 hvec2 __attribute__((ext_vector_type(2)));
typedef _Float16 hvec4 __attribute__((ext_vector_type(4)));
typedef _Float16 hvec8 __attribute__((ext_vector_type(8)));
typedef float f32x4 __attribute__((ext_vector_type(4)));

// v_dot2_f32_f16: p = a.x*b.x + a.y*b.y + c (f32 accumulate)
static __device__ __forceinline__ float fdot2(hvec2 a, hvec2 b, float c) {
#if __has_builtin(__builtin_amdgcn_fdot2)
  return __builtin_amdgcn_fdot2(a, b, c, false);
#else
  return fmaf((float)a.y, (float)b.y, fmaf((float)a.x, (float)b.x, c));
#endif
}

// packed leaky-relu: max(v, 0.2*v)  (v_pk_mul_f16 + v_pk_max_f16)
static __device__ __forceinline__ hvec2 leaky2(hvec2 v) {
  return __builtin_elementwise_max(v, v * (_Float16)0.2f);
}

// ---------------------------------------------------------------------------
// Weight prep: Wh[j2][k] = (j2<J ? Wl[k][j2] : Wr[k][j2-J]) as fp16,
// row-major [2J][K] (MFMA B-operand friendly: col j2 per lane, k contiguous).
// ---------------------------------------------------------------------------
__launch_bounds__(256) __global__
void prepw_kernel(const float* __restrict__ Wl, const float* __restrict__ Wr,
                  __half* __restrict__ Wh, int K_, int J_) {
  const int idx = blockIdx.x * 256 + threadIdx.x;
  if (idx >= 2 * K_ * J_) return;
  const int j2 = idx / K_;
  const int k = idx - j2 * K_;
  const int j = (j2 < J_) ? j2 : j2 - J_;
  const float v = (j2 < J_) ? Wl[k * J_ + j] : Wr[k * J_ + j];
  Wh[idx] = __float2half(v);
}

// ---------------------------------------------------------------------------
// MFMA dual GEMM: O0 = act(A)@W0 (fp16 out), O1 = act(A)@W1 (f32 out).
// Wh = [2J][K] fp16 (prepw). Block: 64 rows x 2J cols, 4 waves (16 rows ea).
// mfma_f32_16x16x32_f16; A/B frags: lane&15 = row/col, k = 8*(lane>>4)+i;
// D: col = lane&15, row = 4*(lane>>4)+reg  [HW-verified layout].
// ---------------------------------------------------------------------------
template <int K, int J, bool FUSE>
__launch_bounds__(256) __global__
void gemm_mfma(const float* __restrict__ A, const __half* __restrict__ Wh,
               const float* __restrict__ bias, __half* __restrict__ O0,
               float* __restrict__ O1, int n) {
  constexpr int BM = 64;
  constexpr int KP = K + 8;  // padded LDS row (fp16 units), 16B-aligned rows
  constexpr int J2 = 2 * J;
  __shared__ __align__(16) __half Alds[BM][KP];
  __shared__ __align__(16) __half Wlds[J2][KP];
  const int tid = threadIdx.x;
  const int n0 = blockIdx.x * BM;

  // stage W (packed global -> padded LDS), b128 copies
  for (int c = tid; c < J2 * (K / 8); c += 256) {
    const int j = c / (K / 8);
    const int k8 = c - j * (K / 8);
    const uint4 w = reinterpret_cast<const uint4*>(Wh)[c];
    *reinterpret_cast<uint4*>(&Wlds[j][k8 * 8]) = w;
  }
  // stage A rows (f32 -> fp16, optional bias+relu), zero-fill OOB
  for (int c = tid; c < BM * (K / 4); c += 256) {
    const int r = c / (K / 4);
    const int k4 = c - r * (K / 4);
    const int row = n0 + r;
    float4 v = make_float4(0.f, 0.f, 0.f, 0.f);
    if (row < n) {
      v = reinterpret_cast<const float4*>(A)[(size_t)row * (K / 4) + k4];
      if constexpr (FUSE) {
        const float4 b = reinterpret_cast<const float4*>(bias)[k4];
        v.x = fmaxf(v.x + b.x, 0.f);
        v.y = fmaxf(v.y + b.y, 0.f);
        v.z = fmaxf(v.z + b.z, 0.f);
        v.w = fmaxf(v.w + b.w, 0.f);
      }
    }
    const hvec4 h = {(_Float16)v.x, (_Float16)v.y, (_Float16)v.z,
                     (_Float16)v.w};
    *reinterpret_cast<hvec4*>(&Alds[r][k4 * 4]) = h;
  }
  __syncthreads();

  const int wv = tid >> 6;  // wave -> 16-row strip
  const int l = tid & 63;
  const int lr = l & 15;    // A row / B col / D col within tile
  const int lk = l >> 4;    // k-subgroup (8 fp16 each)

  hvec8 afrag[K / 32];
#pragma unroll
  for (int kc = 0; kc < K / 32; ++kc)
    afrag[kc] = *reinterpret_cast<const hvec8*>(
        &Alds[wv * 16 + lr][kc * 32 + 8 * lk]);

#pragma unroll
  for (int jt = 0; jt < J2 / 16; ++jt) {
    f32x4 acc = {0.f, 0.f, 0.f, 0.f};
#pragma unroll
    for (int kc = 0; kc < K / 32; ++kc) {
      const hvec8 b = *reinterpret_cast<const hvec8*>(
          &Wlds[jt * 16 + lr][kc * 32 + 8 * lk]);
      acc = __builtin_amdgcn_mfma_f32_16x16x32_f16(afrag[kc], b, acc, 0, 0, 0);
    }
    const int colt = jt * 16 + lr;
    const int rowb = n0 + wv * 16 + 4 * lk;
#pragma unroll
    for (int r = 0; r < 4; ++r) {
      const int row = rowb + r;
      if (row < n) {
        if constexpr (true) {
          if (jt < J / 16)
            O0[(size_t)row * J + colt] = __float2half(acc[r]);
          else
            O1[(size_t)row * J + (colt - J)] = acc[r];
        }
      }
    }
  }
}

// ---------------------------------------------------------------------------
// CSR build: bucket hist (LDS only) -> bucket scan -> partition ->
// per-bucket deg/row/scatter (all per-node RMW in LDS).
// ---------------------------------------------------------------------------
__launch_bounds__(256) __global__
void histB_kernel(const int* __restrict__ ei, int* __restrict__ bhist) {
  __shared__ int lb[NBKT];
  for (int i = threadIdx.x; i < NBKT; i += 256) lb[i] = 0;
  __syncthreads();
  const int e0 = blockIdx.x * 1024 + threadIdx.x;
#pragma unroll
  for (int k = 0; k < 4; ++k) {
    const int e = e0 + k * 256;
    if (e < N_EDGES) atomicAdd(&lb[ei[N_EDGES + e] >> BKT_SHIFT], 1);
  }
  __syncthreads();
  for (int i = threadIdx.x; i < NBKT; i += 256)
    if (lb[i]) atomicAdd(&bhist[i], lb[i]);
}

__launch_bounds__(256) __global__
void bscan_kernel(const int* __restrict__ bhist, int* __restrict__ bbase,
                  int* __restrict__ bcursor) {
  __shared__ int ls[256];
  const int tid = threadIdx.x;
  const int v = (tid < NBKT) ? bhist[tid] : 0;
  ls[tid] = v;
  __syncthreads();
  for (int d = 1; d < 256; d <<= 1) {
    const int t = (tid >= d) ? ls[tid - d] : 0;
    __syncthreads();
    ls[tid] += t;
    __syncthreads();
  }
  if (tid < NBKT) {
    const int ex = ls[tid] - v;
    bbase[tid] = ex;
    bcursor[tid] = ex;
  }
}

// phase A: scatter edges into bucket-contiguous staging (dense writes).
__launch_bounds__(1024) __global__
void partA_kernel(const int* __restrict__ ei, int* __restrict__ bcursor,
                  int2* __restrict__ staging) {
  __shared__ int lh[NBKT];
  __shared__ int lbase[NBKT];
  const int tid = threadIdx.x;
  for (int i = tid; i < NBKT; i += 1024) lh[i] = 0;
  __syncthreads();
  const int e0 = blockIdx.x * 4096 + tid;
  int s[4], d[4];
#pragma unroll
  for (int k = 0; k < 4; ++k) {
    const int e = e0 + k * 1024;
    const bool ok = e < N_EDGES;
    s[k] = ok ? ei[e] : 0;
    d[k] = ok ? ei[N_EDGES + e] : -1;
    if (ok) atomicAdd(&lh[d[k] >> BKT_SHIFT], 1);
  }
  __syncthreads();
  for (int i = tid; i < NBKT; i += 1024) {
    const int c = lh[i];
    lbase[i] = c ? atomicAdd(&bcursor[i], c) : 0;
    lh[i] = 0;
  }
  __syncthreads();
#pragma unroll
  for (int k = 0; k < 4; ++k) {
    if (d[k] >= 0) {
      const int b = d[k] >> BKT_SHIFT;
      const int p = lbase[b] + atomicAdd(&lh[b], 1);
      staging[p] = make_int2(s[k], d[k]);
    }
  }
}

// phase B: per-bucket deg count (LDS), 512-scan -> rowdeg, then local scatter.
__launch_bounds__(256) __global__
void partB_kernel(const int2* __restrict__ staging,
                  const int* __restrict__ bbase, const int* __restrict__ bhist,
                  int2* __restrict__ rowdeg, int* __restrict__ csr_src) {
  __shared__ int ldeg[BKT_NODES];
  __shared__ int lsc[256];
  const int b = blockIdx.x;
  const int tid = threadIdx.x;
  const int node0 = b << BKT_SHIFT;
  ldeg[2 * tid] = 0;
  ldeg[2 * tid + 1] = 0;
  __syncthreads();
  const int start = bbase[b];
  const int cnt = bhist[b];
  for (int i = tid; i < cnt; i += 256)
    atomicAdd(&ldeg[staging[start + i].y - node0], 1);
  __syncthreads();
  // 512-wide exclusive scan (2 elems/thread)
  const int d0 = ldeg[2 * tid];
  const int d1 = ldeg[2 * tid + 1];
  const int psum = d0 + d1;
  lsc[tid] = psum;
  __syncthreads();
  for (int d = 1; d < 256; d <<= 1) {
    const int t = (tid >= d) ? lsc[tid - d] : 0;
    __syncthreads();
    lsc[tid] += t;
    __syncthreads();
  }
  const int ex = lsc[tid] - psum + start;  // global CSR offset
  const int n0 = node0 + 2 * tid;
  if (n0 < N_NODES)   // N even -> n0+1 also < N
    *reinterpret_cast<int4*>(&rowdeg[n0]) = make_int4(ex, d0, ex + d0, d1);
  __syncthreads();
  // reuse ldeg as write cursor
  ldeg[2 * tid] = ex;
  ldeg[2 * tid + 1] = ex + d0;
  __syncthreads();
  for (int i = tid; i < cnt; i += 256) {
    const int2 e = staging[start + i];
    const int p = atomicAdd(&ldeg[e.y - node0], 1);
    csr_src[p] = e.x;
  }
}

// ---------------------------------------------------------------------------
// Layer 1 fused softmax-aggregate. H=2, C=32 (64 ch). One wave per node.
// packed-fp16 math + kstep-granularity wave-uniform guards.
// ---------------------------------------------------------------------------
__launch_bounds__(256) __global__
void gat1_kernel(const __half* __restrict__ xlh, const float* __restrict__ xr,
                 const float* __restrict__ att, const int2* __restrict__ rowdeg,
                 const int* __restrict__ csr_src, float* __restrict__ agg) {
  const int n =
      __builtin_amdgcn_readfirstlane(blockIdx.x * 4 + (threadIdx.x >> 6));
  if (n >= N_NODES) return;
  const int lane = threadIdx.x & 63;
  const int g = lane >> 4;  // edge subgroup 0..3
  const int m = lane & 15;  // channel slice: channels 4m..4m+3 (head = m>>3)
  const int2 rd = rowdeg[n];
  const int r0 = __builtin_amdgcn_readfirstlane(rd.x);
  const int dg = __builtin_amdgcn_readfirstlane(rd.y);

  const float4 xrf =
      *reinterpret_cast<const float4*>(xr + ((size_t)n << 6) + 4 * m);
  const hvec2 xh01 = {(_Float16)xrf.x, (_Float16)xrf.y};
  const hvec2 xh23 = {(_Float16)xrf.z, (_Float16)xrf.w};
  const float4 atf = *reinterpret_cast<const float4*>(att + 4 * m);
  const hvec2 at01 = {(_Float16)atf.x, (_Float16)atf.y};
  const hvec2 at23 = {(_Float16)atf.z, (_Float16)atf.w};

  float s = 0.f, acc0 = 0.f, acc1 = 0.f, acc2 = 0.f, acc3 = 0.f;

  // one kstep = 4 edges (4*q+g); lane gets 8B of xl[src] row (128B/row)
  auto gather1 = [&](int q, int srcv) -> uint2 {
    const int sel = __shfl(srcv, 4 * q + g);
    return *reinterpret_cast<const uint2*>(
        (const char*)xlh + (((size_t)(unsigned)sel) << 7) + 8 * m);
  };
  auto compute1 = [&](int q, uint2 buf, int rem) {
    const hvec2 a01 = __builtin_bit_cast(hvec2, buf.x);
    const hvec2 a23 = __builtin_bit_cast(hvec2, buf.y);
    const hvec2 v01 = leaky2(a01 + xh01);
    const hvec2 v23 = leaky2(a23 + xh23);
    float p = fdot2(v23, at23, fdot2(v01, at01, 0.f));
    p += __shfl_xor(p, 1);
    p += __shfl_xor(p, 2);
    p += __shfl_xor(p, 4);  // 8-lane head-local allreduce
    float e = __expf(p);
    e = (4 * q + g < rem) ? e : 0.f;
    s += e;
    acc0 = fmaf(e, (float)a01.x, acc0);  // v_fma_mix
    acc1 = fmaf(e, (float)a01.y, acc1);
    acc2 = fmaf(e, (float)a23.x, acc2);
    acc3 = fmaf(e, (float)a23.y, acc3);
  };

  for (int c0 = 0; c0 < dg; c0 += 64) {
    const int rem = dg - c0;
    int srcv = 0;
    if (lane < rem) srcv = csr_src[r0 + c0 + lane];  // coalesced, exec-masked
    const int Kc = (min(rem, 64) + 3) >> 2;          // 1..16 ksteps
#pragma unroll
    for (int g0 = 0; g0 < 16; g0 += 4) {
      if (g0 < Kc) {  // wave-uniform (scalar branch)
        uint2 B[4];
#pragma unroll
        for (int k = 0; k < 4; ++k)
          if (g0 + k < Kc) B[k] = gather1(g0 + k, srcv);
#pragma unroll
        for (int k = 0; k < 4; ++k)
          if (g0 + k < Kc) compute1(g0 + k, B[k], rem);
      }
    }
  }

  // merge the 4 edge subgroups (lane bits 4,5)
  s += __shfl_xor(s, 16);
  s += __shfl_xor(s, 32);
  acc0 += __shfl_xor(acc0, 16);
  acc0 += __shfl_xor(acc0, 32);
  acc1 += __shfl_xor(acc1, 16);
  acc1 += __shfl_xor(acc1, 32);
  acc2 += __shfl_xor(acc2, 16);
  acc2 += __shfl_xor(acc2, 32);
  acc3 += __shfl_xor(acc3, 16);
  acc3 += __shfl_xor(acc3, 32);
  const float inv = s > 0.f ? 1.f / s : 0.f;
  if (g == 0)
    *reinterpret_cast<float4*>(agg + ((size_t)n << 6) + 4 * m) =
        make_float4(acc0 * inv, acc1 * inv, acc2 * inv, acc3 * inv);
}

// ---------------------------------------------------------------------------
// Layer 2 fused: H=1, C=32. packed-fp16 + kstep guards (8 edges/kstep).
// Epilogue: bias+relu -> h2; gate matvec split across wave halves.
// ---------------------------------------------------------------------------
__launch_bounds__(256) __global__
void gat2_kernel(const __half* __restrict__ xlh, const float* __restrict__ xr,
                 const float* __restrict__ att, const int2* __restrict__ rowdeg,
                 const int* __restrict__ csr_src,
                 const float* __restrict__ b2, const float* __restrict__ g1w,
                 const float* __restrict__ g1b, const float* __restrict__ g2w,
                 const float* __restrict__ g2b, float* __restrict__ h2,
                 float* __restrict__ gate) {
  const int n =
      __builtin_amdgcn_readfirstlane(blockIdx.x * 4 + (threadIdx.x >> 6));
  if (n >= N_NODES) return;
  const int lane = threadIdx.x & 63;
  const int g = lane >> 3;  // edge subgroup 0..7
  const int m = lane & 7;   // channel slice: channels 4m..4m+3
  const int2 rd = rowdeg[n];
  const int r0 = __builtin_amdgcn_readfirstlane(rd.x);
  const int dg = __builtin_amdgcn_readfirstlane(rd.y);

  const float4 xrf =
      *reinterpret_cast<const float4*>(xr + (size_t)n * 32 + 4 * m);
  const hvec2 xh01 = {(_Float16)xrf.x, (_Float16)xrf.y};
  const hvec2 xh23 = {(_Float16)xrf.z, (_Float16)xrf.w};
  const float4 atf = *reinterpret_cast<const float4*>(att + 4 * m);
  const hvec2 at01 = {(_Float16)atf.x, (_Float16)atf.y};
  const hvec2 at23 = {(_Float16)atf.z, (_Float16)atf.w};

  float s = 0.f, acc0 = 0.f, acc1 = 0.f, acc2 = 0.f, acc3 = 0.f;

  // one kstep = 8 edges (8*q+g); lane gets 8B of xl[src] row (64B/row)
  auto gather1 = [&](int q, int srcv) -> uint2 {
    const int sel = __shfl(srcv, 8 * q + g);
    return *reinterpret_cast<const uint2*>(
        (const char*)xlh + (((size_t)(unsigned)sel) << 6) + 8 * m);
  };
  auto compute1 = [&](int q, uint2 buf, int rem) {
    const hvec2 a01 = __builtin_bit_cast(hvec2, buf.x);
    const hvec2 a23 = __builtin_bit_cast(hvec2, buf.y);
    const hvec2 v01 = leaky2(a01 + xh01);
    const hvec2 v23 = leaky2(a23 + xh23);
    float p = fdot2(v23, at23, fdot2(v01, at01, 0.f));
    p += __shfl_xor(p, 1);
    p += __shfl_xor(p, 2);
    p += __shfl_xor(p, 4);  // 8-lane (full channel) allreduce
    float e = __expf(p);
    e = (8 * q + g < rem) ? e : 0.f;
    s += e;
    acc0 = fmaf(e, (float)a01.x, acc0);
    acc1 = fmaf(e, (float)a01.y, acc1);
    acc2 = fmaf(e, (float)a23.x, acc2);
    acc3 = fmaf(e, (float)a23.y, acc3);
  };

  for (int c0 = 0; c0 < dg; c0 += 64) {
    const int rem = dg - c0;
    int srcv = 0;
    if (lane < rem) srcv = csr_src[r0 + c0 + lane];
    const int Kc = (min(rem, 64) + 7) >> 3;  // 1..8 ksteps
#pragma unroll
    for (int g0 = 0; g0 < 8; g0 += 4) {
      if (g0 < Kc) {  // wave-uniform
        uint2 B[4];
#pragma unroll
        for (int k = 0; k < 4; ++k)
          if (g0 + k < Kc) B[k] = gather1(g0 + k, srcv);
#pragma unroll
        for (int k = 0; k < 4; ++k)
          if (g0 + k < Kc) compute1(g0 + k, B[k], rem);
      }
    }
  }

  // merge the 8 edge subgroups (lane bits 3,4,5)
  s += __shfl_xor(s, 8);
  s += __shfl_xor(s, 16);
  s += __shfl_xor(s, 32);
  acc0 += __shfl_xor(acc0, 8);
  acc0 += __shfl_xor(acc0, 16);
  acc0 += __shfl_xor(acc0, 32);
  acc1 += __shfl_xor(acc1, 8);
  acc1 += __shfl_xor(acc1, 16);
  acc1 += __shfl_xor(acc1, 32);
  acc2 += __shfl_xor(acc2, 8);
  acc2 += __shfl_xor(acc2, 16);
  acc2 += __shfl_xor(acc2, 32);
  acc3 += __shfl_xor(acc3, 8);
  acc3 += __shfl_xor(acc3, 16);
  acc3 += __shfl_xor(acc3, 32);
  const float inv = s > 0.f ? 1.f / s : 0.f;
  const float4 b2v = *reinterpret_cast<const float4*>(b2 + 4 * m);
  const float h0 = fmaxf(fmaf(acc0, inv, b2v.x), 0.f);
  const float h1 = fmaxf(fmaf(acc1, inv, b2v.y), 0.f);
  const float h2v = fmaxf(fmaf(acc2, inv, b2v.z), 0.f);
  const float h3 = fmaxf(fmaf(acc3, inv, b2v.w), 0.f);
  if (g == 0)
    *reinterpret_cast<float4*>(h2 + (size_t)n * 32 + 4 * m) =
        make_float4(h0, h1, h2v, h3);

  // redistribute to 1-channel-per-lane (c = lane&31) for the gate matvec
  const int c = lane & 31;
  const float t0 = __shfl(h0, c >> 2, 8);
  const float t1 = __shfl(h1, c >> 2, 8);
  const float t2 = __shfl(h2v, c >> 2, 8);
  const float t3 = __shfl(h3, c >> 2, 8);
  const float hv = (c & 2) ? ((c & 1) ? t3 : t2) : ((c & 1) ? t1 : t0);
  // split the 32-k dot across the two 32-lane halves: 16 iters each
  const int k0 = (lane >> 5) << 4;  // 0 or 16
  float sg = 0.f;
#pragma unroll
  for (int k = 0; k < 16; ++k) {
    const int kk = k0 + k;
    sg = fmaf(__shfl(hv, kk, 32), g1w[kk * 32 + c], sg);
  }
  sg += __shfl_xor(sg, 32);  // merge halves
  sg = fmaxf(sg + g1b[c], 0.f);
  float pg = sg * g2w[c];
  pg += __shfl_xor(pg, 1);
  pg += __shfl_xor(pg, 2);
  pg += __shfl_xor(pg, 4);
  pg += __shfl_xor(pg, 8);
  pg += __shfl_xor(pg, 16);
  if (lane == 0) gate[n] = pg + g2b[0];
}

// ---------------------------------------------------------------------------
__launch_bounds__(256) __global__
void gepool_kernel(const float* __restrict__ h2, const int* __restrict__ batch,
                   const float* __restrict__ gate, float* __restrict__ gd,
                   float* __restrict__ pooled) {
  __shared__ float pool[G_GRAPHS * 32];
  __shared__ float gdb[G_GRAPHS];
  const int tid = threadIdx.x;
  for (int i = tid; i < G_GRAPHS * 32; i += 256) pool[i] = 0.f;
  if (tid < G_GRAPHS) gdb[tid] = 0.f;
  __syncthreads();
  const int c = tid & 31;
  const int hw = tid >> 5;
  const int start = blockIdx.x * 256;
  const int end = min(N_NODES, start + 256);
  for (int n = start + hw; n < end; n += 8) {
    const int b = batch[n];
    const float ge = __expf(gate[n]);
    atomicAdd(&pool[b * 32 + c], ge * h2[(size_t)n * 32 + c]);
    if (c == 0) atomicAdd(&gdb[b], ge);
  }
  __syncthreads();
  for (int i = tid; i < G_GRAPHS * 32; i += 256)
    if (pool[i] != 0.f) unsafeAtomicAdd(&pooled[i], pool[i]);
  if (tid < G_GRAPHS && gdb[tid] != 0.f) unsafeAtomicAdd(&gd[tid], gdb[tid]);
}

__launch_bounds__(64) __global__
void final_kernel(const float* __restrict__ pooled, const float* __restrict__ gd,
                  const float* __restrict__ l1w, const float* __restrict__ l1b,
                  const float* __restrict__ l2w, const float* __restrict__ l2b,
                  float* __restrict__ out) {
  const int g = blockIdx.x;
  const int lane = threadIdx.x;
  if (lane >= 32) return;
  const float invgd = 1.f / gd[g];
  float s = l1b[lane];
#pragma unroll
  for (int k = 0; k < 32; ++k)
    s = fmaf(pooled[g * 32 + k] * invgd, l1w[k * 32 + lane], s);
  s = fmaxf(s, 0.f);
  float p = s * l2w[lane];
  p += __shfl_xor(p, 1);
  p += __shfl_xor(p, 2);
  p += __shfl_xor(p, 4);
  p += __shfl_xor(p, 8);
  p += __shfl_xor(p, 16);
  if (lane == 0) out[g] = p + l2b[0];
}

// ---------------------------------------------------------------------------
extern "C" void kernel_launch(void* const* d_in, const int* in_sizes, int n_in,
                              void* d_out, int out_size, void* d_ws,
                              size_t ws_size, hipStream_t stream) {
  const float* x    = (const float*)d_in[0];
  const int*   ei   = (const int*)d_in[1];
  const int*   batch= (const int*)d_in[2];
  const float* Wl1  = (const float*)d_in[3];
  const float* Wr1  = (const float*)d_in[4];
  const float* att1 = (const float*)d_in[5];
  const float* b1   = (const float*)d_in[6];
  const float* Wl2  = (const float*)d_in[7];
  const float* Wr2  = (const float*)d_in[8];
  const float* att2 = (const float*)d_in[9];
  const float* b2   = (const float*)d_in[10];
  const float* g1w  = (const float*)d_in[11];
  const float* g1b  = (const float*)d_in[12];
  const float* g2w  = (const float*)d_in[13];
  const float* g2b  = (const float*)d_in[14];
  const float* l1w  = (const float*)d_in[15];
  const float* l1b  = (const float*)d_in[16];
  const float* l2w  = (const float*)d_in[17];
  const float* l2b  = (const float*)d_in[18];
  float* out = (float*)d_out;

  // ---- workspace layout ----
  int* bhist   = (int*)d_ws;            // NBKT (zeroed)
  int* bbase   = bhist + NBKT;          // NBKT
  int* bcursor = bbase + NBKT;          // NBKT
  int2* rowdeg = (int2*)(bcursor + NBKT);            // N int2 {row, deg}
  int* csr_src = (int*)(rowdeg + N_NODES);           // E + 16 pad
  int2* staging = (int2*)(csr_src + N_EDGES + 16);   // E int2
  float* fbase = (float*)(staging + N_EDGES);
  float* xr1  = fbase;                         // N*64
  float* agg1 = xr1 + (size_t)N_NODES * 64;    // N*64
  float* gate = agg1 + (size_t)N_NODES * 64;   // N
  float* gd   = gate + N_NODES;                // 64
  float* pooled = gd + G_GRAPHS;               // 64*32
  __half* xl1h = (__half*)(pooled + G_GRAPHS * 32);  // N*64 half
  // layer-2 aliases (stream-ordered producers/consumers)
  __half* xl2h = xl1h;                         // N*32 half
  float* xr2 = xr1;                            // N*32 (first half of xr1)
  float* h2  = xr1 + (size_t)N_NODES * 32;     // N*32 (second half of xr1)
  // fp16 weight staging lives in the gate region (dead until gat2 writes it;
  // both gemms consume Wh before gat2 runs). 128*128 + 64*64 halves = 40KB.
  __half* Wh1 = (__half*)gate;                 // [128][128] fp16
  __half* Wh2 = Wh1 + 128 * 128;               // [64][64] fp16

  (void)hipMemsetAsync(bhist, 0, (size_t)NBKT * sizeof(int), stream);
  (void)hipMemsetAsync(gd, 0,
                       (size_t)(G_GRAPHS + G_GRAPHS * 32) * sizeof(float),
                       stream);

  // fp16 weight prep (no deps on CSR)
  prepw_kernel<<<(2 * 128 * 64 + 255) / 256, 256, 0, stream>>>(Wl1, Wr1, Wh1,
                                                               128, 64);
  prepw_kernel<<<(2 * 64 * 32 + 255) / 256, 256, 0, stream>>>(Wl2, Wr2, Wh2,
                                                              64, 32);

  // CSR build: bucket hist -> scan -> partition -> per-bucket deg/row/scatter
  histB_kernel<<<(N_EDGES + 1023) / 1024, 256, 0, stream>>>(ei, bhist);
  bscan_kernel<<<1, 256, 0, stream>>>(bhist, bbase, bcursor);
  partA_kernel<<<(N_EDGES + 4095) / 4096, 1024, 0, stream>>>(ei, bcursor,
                                                             staging);
  partB_kernel<<<NBKT, 256, 0, stream>>>(staging, bbase, bhist, rowdeg,
                                         csr_src);

  // Layer 1 (MFMA dual GEMM: xl fp16, xr f32)
  gemm_mfma<128, 64, false><<<(N_NODES + 63) / 64, 256, 0, stream>>>(
      x, Wh1, nullptr, xl1h, xr1, N_NODES);
  gat1_kernel<<<(N_NODES + 3) / 4, 256, 0, stream>>>(xl1h, xr1, att1, rowdeg,
                                                     csr_src, agg1);

  // Layer 2 (bias1+relu fused into A staging; gate fused into gat2 epilogue)
  gemm_mfma<64, 32, true><<<(N_NODES + 63) / 64, 256, 0, stream>>>(
      agg1, Wh2, b1, xl2h, xr2, N_NODES);
  gat2_kernel<<<(N_NODES + 3) / 4, 256, 0, stream>>>(
      xl2h, xr2, att2, rowdeg, csr_src, b2, g1w, g1b, g2w, g2b, h2, gate);

  // Pooling + head (no-max graph softmax)
  gepool_kernel<<<(N_NODES + 255) / 256, 256, 0, stream>>>(h2, batch, gate, gd,
                                                           pooled);
  final_kernel<<<64, 64, 0, stream>>>(pooled, gd, l1w, l1b, l2w, l2b, out);
}